// Round 4
// baseline (194.935 us; speedup 1.0000x reference)
//
#include <hip/hip_runtime.h>
#include <hip/hip_bf16.h>
#include <cstdint>
#include <math.h>

// Problem constants
#define DM   1024
#define NH   16
#define DH   64
#define BB   4
#define TT   2048
#define MTOT (BB*TT)   // 8192 rows

using short8 = __attribute__((ext_vector_type(8))) short;  // 8 bf16 (4 VGPRs)
using f32x4  = __attribute__((ext_vector_type(4))) float;

__device__ __forceinline__ f32x4 mfma16(short8 a, short8 b, f32x4 c) {
  return __builtin_amdgcn_mfma_f32_16x16x32_bf16(a, b, c, 0, 0, 0);
}

typedef const __attribute__((address_space(1))) unsigned int* as1_u32p;
typedef __attribute__((address_space(3))) unsigned int*       as3_u32p;

// async global->LDS, 16B per lane; LDS dest = wave-uniform base + lane*16 (linear)
__device__ __forceinline__ void gl_lds16(const void* g, void* l) {
  __builtin_amdgcn_global_load_lds(
      (as1_u32p)(reinterpret_cast<uintptr_t>(g)),
      (as3_u32p)((unsigned int)(reinterpret_cast<uintptr_t>(l))),
      16, 0, 0);
}

// XOR swizzle for tiles with 64-elem (128B) rows: 8 slots of 8 bf16; slot ^= row&7
__device__ __forceinline__ int swz64(int row, int col) {
  return row*64 + ((((col >> 3) ^ (row & 7)) << 3) | (col & 7));
}

__device__ __forceinline__ unsigned pkbf(float a, float b) {
  __hip_bfloat162 h = __float22bfloat162_rn(make_float2(a, b)); // x=lo, y=hi
  return *reinterpret_cast<unsigned*>(&h);
}

#define VMW(n) asm volatile("s_waitcnt vmcnt(" #n ")" ::: "memory")

// ---------------- fp32 -> bf16 copy convert ----------------
__global__ __launch_bounds__(256) void k_cvt(const float* __restrict__ in,
                                             __hip_bfloat16* __restrict__ out, int n8) {
  int i = blockIdx.x * 256 + threadIdx.x;
  if (i >= n8) return;
  const float* p = in + (size_t)i * 8;
  short8 o;
#pragma unroll
  for (int j = 0; j < 8; ++j) {
    __hip_bfloat16 h = __float2bfloat16(p[j]);
    o[j] = *reinterpret_cast<short*>(&h);
  }
  *reinterpret_cast<short8*>(out + (size_t)i * 8) = o;
}

// ---------------- W [K][N] fp32 -> Wt [N][K] bf16 (tiled transpose) ----------------
__global__ __launch_bounds__(256) void k_transpose_cvt(const float* __restrict__ W,
                                                       __hip_bfloat16* __restrict__ Wt,
                                                       int K, int N) {
  __shared__ float tbuf[32][33];
  const int n0 = blockIdx.x * 32, k0 = blockIdx.y * 32;
  const int tx = threadIdx.x & 31, ty = threadIdx.x >> 5;
#pragma unroll
  for (int i = 0; i < 4; ++i)
    tbuf[ty + i*8][tx] = W[(size_t)(k0 + ty + i*8) * N + n0 + tx];
  __syncthreads();
#pragma unroll
  for (int i = 0; i < 4; ++i)
    Wt[(size_t)(n0 + ty + i*8) * K + k0 + tx] = __float2bfloat16(tbuf[tx][ty + i*8]);
}

// ---------------- 256x256 8-phase bf16 GEMM (QKV): A[8192][1024] @ Wt[3072][1024]^T ----------------
// 8 waves; per phase all waves compute one 128x128 C-quadrant (wave slice 32x64, 16 MFMA).
// Double-buffered LDS (128 KiB), half-tile staging via global_load_lds, counted vmcnt(4)
// before each end-of-phase barrier (never vmcnt(0) in steady state).
// Epilogue scatters to Q (pre-scaled by 0.125*log2e), K, Vt.
#define PH_READ_A(dst, mhh) \
  _Pragma("unroll") for (int mi = 0; mi < 2; ++mi) \
  _Pragma("unroll") for (int ks = 0; ks < 2; ++ks) \
    dst[mi][ks] = *reinterpret_cast<const short8*>(Ab + (mhh)*8192 + arow + mi*1024 + (fb ^ (ks*32)));

#define PH_READ_B(dst, nhh) \
  _Pragma("unroll") for (int ni = 0; ni < 4; ++ni) \
  _Pragma("unroll") for (int ks = 0; ks < 2; ++ks) \
    dst[ni][ks] = *reinterpret_cast<const short8*>(Bb + (nhh)*8192 + brow + ni*1024 + (fb ^ (ks*32)));

#define PH_MFMA(mhh, nhh, av, bvv) \
  __builtin_amdgcn_s_setprio(1); \
  _Pragma("unroll") for (int mi = 0; mi < 2; ++mi) \
  _Pragma("unroll") for (int ni = 0; ni < 4; ++ni) \
  _Pragma("unroll") for (int ks = 0; ks < 2; ++ks) \
    acc[mhh][nhh][mi][ni] = mfma16(av[mi][ks], bvv[ni][ks], acc[mhh][nhh][mi][ni]); \
  __builtin_amdgcn_s_setprio(0);

__global__ __launch_bounds__(512, 2) void k_gemm256(const __hip_bfloat16* __restrict__ A,
                                                    const __hip_bfloat16* __restrict__ Bt,
                                                    const float* __restrict__ bias,
                                                    __hip_bfloat16* __restrict__ Qb,
                                                    __hip_bfloat16* __restrict__ Kb,
                                                    __hip_bfloat16* __restrict__ Vtb) {
  __shared__ __hip_bfloat16 As[2][256 * 64];
  __shared__ __hip_bfloat16 Bs[2][256 * 64];
  const int tid = threadIdx.x;
  const int l = tid & 63, w = tid >> 6;
  const int lr = l & 15, lg = l >> 4;
  const int qm = w >> 1, qn = w & 1;           // wave slice within quadrant: 4x32 rows, 2x64 cols
  const int m0 = blockIdx.x * 256, n0 = blockIdx.y * 256;

  // staging per-thread constants (pre-swizzled source, linear LDS dest)
  size_t aoff[2], boff[2];
  int lfo[2];
#pragma unroll
  for (int i = 0; i < 2; ++i) {
    int f = i * 4096 + tid * 8;
    int row = f >> 6;
    int lcol = ((((f >> 3) & 7) ^ (row & 7)) << 3);
    aoff[i] = (size_t)(m0 + row) * 1024 + lcol;
    boff[i] = (size_t)(n0 + row) * 1024 + lcol;
    lfo[i] = f;
  }
  // stage half h of tile t into buffer b: h 0=A-low,1=B-low,2=A-high,3=B-high
  auto stage = [&](int h, int t, int b) {
    const int k0 = t * 64;
    if (h == 0) {
      gl_lds16(A + aoff[0] + k0, &As[b][lfo[0]]);
      gl_lds16(A + aoff[1] + k0, &As[b][lfo[1]]);
    } else if (h == 1) {
      gl_lds16(Bt + boff[0] + k0, &Bs[b][lfo[0]]);
      gl_lds16(Bt + boff[1] + k0, &Bs[b][lfo[1]]);
    } else if (h == 2) {
      gl_lds16(A + aoff[0] + 128 * 1024 + k0, &As[b][8192 + lfo[0]]);
      gl_lds16(A + aoff[1] + 128 * 1024 + k0, &As[b][8192 + lfo[1]]);
    } else {
      gl_lds16(Bt + boff[0] + 128 * 1024 + k0, &Bs[b][8192 + lfo[0]]);
      gl_lds16(Bt + boff[1] + 128 * 1024 + k0, &Bs[b][8192 + lfo[1]]);
    }
  };

  // frag read bases (element indices)
  const int fb = lr * 64 + ((lg ^ (lr & 7)) << 3);
  const int arow = qm * 2048;    // qm*32 rows * 64
  const int brow = qn * 4096;    // qn*64 rows * 64

  // prologue: stage tile 0 (A0,B0,A1,B1), publish A0,B0
  stage(0, 0, 0); stage(1, 0, 0); stage(2, 0, 0); stage(3, 0, 0);
  VMW(4);
  __builtin_amdgcn_s_barrier();

  f32x4 acc[2][2][2][4] = {};
  short8 a0[2][2], a1[2][2], b0[4][2], b1[4][2];

  for (int t = 0; t < 16; ++t) {
    const int cur = t & 1, nxt = cur ^ 1;
    const bool pf = (t < 15);
    const __hip_bfloat16* Ab = As[cur];
    const __hip_bfloat16* Bb = Bs[cur];
    // ---- phase 0: quadrant (A0,B0); stage A0' ----
    PH_READ_A(a0, 0);
    PH_READ_B(b0, 0);
    if (pf) stage(0, t + 1, nxt);
    __builtin_amdgcn_s_barrier();
    PH_MFMA(0, 0, a0, b0);
    if (pf) { VMW(4); } else { VMW(2); }
    __builtin_amdgcn_s_barrier();
    // ---- phase 1: quadrant (A1,B0); stage B0' ----
    PH_READ_A(a1, 1);
    if (pf) stage(1, t + 1, nxt);
    __builtin_amdgcn_s_barrier();
    PH_MFMA(1, 0, a1, b0);
    if (pf) { VMW(4); } else { VMW(0); }
    __builtin_amdgcn_s_barrier();
    // ---- phase 2: quadrant (A0,B1); stage A1' ----
    PH_READ_B(b1, 1);
    if (pf) stage(2, t + 1, nxt);
    __builtin_amdgcn_s_barrier();
    PH_MFMA(0, 1, a0, b1);
    if (pf) { VMW(4); }
    __builtin_amdgcn_s_barrier();
    // ---- phase 3: quadrant (A1,B1); stage B1' ----
    if (pf) stage(3, t + 1, nxt);
    __builtin_amdgcn_s_barrier();
    PH_MFMA(1, 1, a1, b1);
    if (pf) { VMW(4); }
    __builtin_amdgcn_s_barrier();
  }

  // epilogue: scatter to Q / K / Vt with bias
  const float qs = 0.18033688011112042f;  // 0.125 * log2(e) folded into Q
#pragma unroll
  for (int nh = 0; nh < 2; ++nh) {
#pragma unroll
    for (int ni = 0; ni < 4; ++ni) {
      const int col = n0 + nh * 128 + qn * 64 + ni * 16 + lr;
      const float bv = bias[col];
      const int which = col >> 10;
      const int hh = (col >> 6) & 15;
      const int dd = col & 63;
#pragma unroll
      for (int mh = 0; mh < 2; ++mh) {
#pragma unroll
        for (int mi = 0; mi < 2; ++mi) {
#pragma unroll
          for (int r = 0; r < 4; ++r) {
            const int row = m0 + mh * 128 + qm * 32 + mi * 16 + lg * 4 + r;
            const int b = row >> 11, tt = row & 2047;
            float v = acc[mh][nh][mi][ni][r] + bv;
            if (which == 0) v *= qs;
            const __hip_bfloat16 hv = __float2bfloat16(v);
            const size_t bh = (size_t)b * 16 + hh;
            if (which == 0)      Qb[(bh * TT + tt) * 64 + dd] = hv;
            else if (which == 1) Kb[(bh * TT + tt) * 64 + dd] = hv;
            else                 Vtb[(bh * 64 + dd) * TT + tt] = hv;
          }
        }
      }
    }
  }
}

// ---------------- 128x128 bf16 GEMM (proj): A[M][1024] @ Bt[N][1024]^T + bias -> fp32 ----------------
__global__ __launch_bounds__(256) void k_gemm(const __hip_bfloat16* __restrict__ A,
                                              const __hip_bfloat16* __restrict__ Bt,
                                              const float* __restrict__ bias,
                                              float* __restrict__ outF) {
  __shared__ __hip_bfloat16 As[128 * 64];
  __shared__ __hip_bfloat16 Bs[128 * 64];
  const int tid = threadIdx.x;
  const int l = tid & 63, w = tid >> 6;
  const int lr = l & 15, lg = l >> 4;
  const int wr = w >> 1, wc = w & 1;
  const int m0 = blockIdx.x * 128, n0 = blockIdx.y * 128;
  f32x4 acc[4][4] = {};
  for (int k0 = 0; k0 < 1024; k0 += 64) {
#pragma unroll
    for (int it = 0; it < 4; ++it) {
      int e = it * 2048 + tid * 8;
      int row = e >> 6;
      int lcol = ((((e >> 3) & 7) ^ (row & 7)) << 3);
      gl_lds16(A + (size_t)(m0 + row) * 1024 + k0 + lcol, &As[e]);
    }
#pragma unroll
    for (int it = 0; it < 4; ++it) {
      int e = it * 2048 + tid * 8;
      int row = e >> 6;
      int lcol = ((((e >> 3) & 7) ^ (row & 7)) << 3);
      gl_lds16(Bt + (size_t)(n0 + row) * 1024 + k0 + lcol, &Bs[e]);
    }
    __syncthreads();
#pragma unroll
    for (int ks = 0; ks < 2; ++ks) {
      short8 af[4], bf[4];
#pragma unroll
      for (int m = 0; m < 4; ++m)
        af[m] = *reinterpret_cast<const short8*>(&As[swz64(wr*64 + m*16 + lr, ks*32 + lg*8)]);
#pragma unroll
      for (int n = 0; n < 4; ++n)
        bf[n] = *reinterpret_cast<const short8*>(&Bs[swz64(wc*64 + n*16 + lr, ks*32 + lg*8)]);
#pragma unroll
      for (int m = 0; m < 4; ++m)
#pragma unroll
        for (int n = 0; n < 4; ++n)
          acc[m][n] = mfma16(af[m], bf[n], acc[m][n]);
    }
    __syncthreads();
  }
#pragma unroll
  for (int n = 0; n < 4; ++n) {
    const int col = n0 + wc*64 + n*16 + lr;
    const float bv = bias[col];
#pragma unroll
    for (int m = 0; m < 4; ++m)
#pragma unroll
      for (int r = 0; r < 4; ++r) {
        const int row = m0 + wr*64 + m*16 + lg*4 + r;
        outF[(size_t)row * 1024 + col] = acc[m][n][r] + bv;
      }
  }
}

// ---------------- causal flash attention (paired q-tiles, fixed-max softmax) ----------------
__device__ __forceinline__ void attn_chunks(const __hip_bfloat16* __restrict__ Klds,
                                            const __hip_bfloat16* __restrict__ Vtlds,
                                            int ka, int va0, int va1, int va2, int va3,
                                            int kv0, int kmaxw, int qm,
                                            short8 qf0, short8 qf1,
                                            f32x4 (&acc)[4], float& lrun) {
  const int vak[4] = {va0, va1, va2, va3};
#pragma unroll
  for (int kci = 0; kci < 4; ++kci) {
    const int kbase = kv0 + kci * 32;
    if (kbase > kmaxw) break;          // wave-uniform causal skip
    f32x4 s0 = {}, s1 = {};
    {
      const int kb = ka + kci * 2048;
      short8 kf00 = *reinterpret_cast<const short8*>(&Klds[kb]);
      short8 kf10 = *reinterpret_cast<const short8*>(&Klds[kb + 1024]);
      short8 kf01 = *reinterpret_cast<const short8*>(&Klds[kb ^ 32]);
      short8 kf11 = *reinterpret_cast<const short8*>(&Klds[(kb + 1024) ^ 32]);
      s0 = mfma16(kf00, qf0, s0);
      s1 = mfma16(kf10, qf0, s1);
      s0 = mfma16(kf01, qf1, s0);
      s1 = mfma16(kf11, qf1, s1);
    }
    if (kbase + 31 > kmaxw - 15) {     // diagonal chunk: per-element causal mask
#pragma unroll
      for (int r = 0; r < 4; ++r) {
        if (kbase + r > qm)      s0[r] = -INFINITY;
        if (kbase + 16 + r > qm) s1[r] = -INFINITY;
      }
    }
    float p0 = __builtin_amdgcn_exp2f(s0[0]), p1 = __builtin_amdgcn_exp2f(s0[1]);
    float p2 = __builtin_amdgcn_exp2f(s0[2]), p3 = __builtin_amdgcn_exp2f(s0[3]);
    float p4 = __builtin_amdgcn_exp2f(s1[0]), p5 = __builtin_amdgcn_exp2f(s1[1]);
    float p6 = __builtin_amdgcn_exp2f(s1[2]), p7 = __builtin_amdgcn_exp2f(s1[3]);
    lrun += ((p0 + p1) + (p2 + p3)) + ((p4 + p5) + (p6 + p7));
    unsigned u0 = pkbf(p0, p1);
    unsigned u1 = pkbf(p2, p3);
    unsigned u2 = pkbf(p4, p5);
    unsigned u3 = pkbf(p6, p7);
    const int l = threadIdx.x & 63;
    const int lr = l & 15, lg = l >> 4;
    const int sa = (((lg & 1) << 1) << 4) + lr;
    const int sb = sa + 16;
    unsigned va_0 = (unsigned)__shfl((int)u0, sa), va_1 = (unsigned)__shfl((int)u1, sa);
    unsigned va_2 = (unsigned)__shfl((int)u2, sa), va_3 = (unsigned)__shfl((int)u3, sa);
    unsigned vb_0 = (unsigned)__shfl((int)u0, sb), vb_1 = (unsigned)__shfl((int)u1, sb);
    unsigned vb_2 = (unsigned)__shfl((int)u2, sb), vb_3 = (unsigned)__shfl((int)u3, sb);
    const bool hi = lg >= 2;
    union { unsigned u[4]; short8 s; } pw;
    pw.u[0] = hi ? va_2 : va_0;
    pw.u[1] = hi ? va_3 : va_1;
    pw.u[2] = hi ? vb_2 : vb_0;
    pw.u[3] = hi ? vb_3 : vb_1;
    const short8 pf = pw.s;
    const int vb = vak[kci];
    short8 v0 = *reinterpret_cast<const short8*>(&Vtlds[vb]);
    short8 v1 = *reinterpret_cast<const short8*>(&Vtlds[vb + 2048]);
    short8 v2 = *reinterpret_cast<const short8*>(&Vtlds[vb + 4096]);
    short8 v3 = *reinterpret_cast<const short8*>(&Vtlds[vb + 6144]);
    acc[0] = mfma16(v0, pf, acc[0]);
    acc[1] = mfma16(v1, pf, acc[1]);
    acc[2] = mfma16(v2, pf, acc[2]);
    acc[3] = mfma16(v3, pf, acc[3]);
  }
}

__device__ __forceinline__ void store_tile(__hip_bfloat16* Ylds, f32x4 (&acc)[4],
                                           float lrun, int q0, int w, int l,
                                           int lr, int lg, int bh,
                                           __hip_bfloat16* __restrict__ Y) {
  lrun += __shfl_xor(lrun, 16);
  lrun += __shfl_xor(lrun, 32);
  const float inv = 1.f / lrun;
#pragma unroll
  for (int nb = 0; nb < 4; ++nb) {
#pragma unroll
    for (int r = 0; r < 4; ++r) {
      const int d = nb * 16 + lg * 4 + r;
      Ylds[swz64(lr, d)] = __float2bfloat16(acc[nb][r] * inv);
    }
  }
  const int rr = l >> 2, part = l & 3;
  const int trow = q0 + w * 16 + rr;
  const int b = bh >> 4, h = bh & 15;
  short8 y0 = *reinterpret_cast<const short8*>(&Ylds[swz64(rr, part * 16)]);
  short8 y1 = *reinterpret_cast<const short8*>(&Ylds[swz64(rr, part * 16 + 8)]);
  __hip_bfloat16* dst = Y + ((size_t)b * TT + trow) * 1024 + h * 64 + part * 16;
  *reinterpret_cast<short8*>(dst) = y0;
  *reinterpret_cast<short8*>(dst + 8) = y1;
}

__global__ __launch_bounds__(256, 4) void k_flash(const __hip_bfloat16* __restrict__ Qb,
                                                  const __hip_bfloat16* __restrict__ Kb,
                                                  const __hip_bfloat16* __restrict__ Vtb,
                                                  __hip_bfloat16* __restrict__ Y) {
  __shared__ __hip_bfloat16 Klds[128 * 64];
  __shared__ __hip_bfloat16 Vtlds[64 * 128];
  const int tid = threadIdx.x;
  const int l = tid & 63, w = tid >> 6;
  const int lr = l & 15, lg = l >> 4;
  const int p  = blockIdx.x >> 6;       // pair index 0..15
  const int bh = blockIdx.x & 63;
  const int q0A = p * 64, q0B = (31 - p) * 64;
  const __hip_bfloat16* Qp = Qb + (size_t)bh * TT * 64;
  const __hip_bfloat16* Kp = Kb + (size_t)bh * TT * 64;
  const __hip_bfloat16* Vp = Vtb + (size_t)bh * 64 * TT;
  const int qrowA = q0A + w * 16 + lr;
  const int qrowB = q0B + w * 16 + lr;
  const short8 qfA0 = *reinterpret_cast<const short8*>(Qp + (size_t)qrowA * 64 + lg * 8);
  const short8 qfA1 = *reinterpret_cast<const short8*>(Qp + (size_t)qrowA * 64 + 32 + lg * 8);
  const short8 qfB0 = *reinterpret_cast<const short8*>(Qp + (size_t)qrowB * 64 + lg * 8);
  const short8 qfB1 = *reinterpret_cast<const short8*>(Qp + (size_t)qrowB * 64 + 32 + lg * 8);
  f32x4 accA[4] = {}, accB[4] = {};
  float lA = 0.f, lB = 0.f;

  const int ka  = lr * 64 + ((lg ^ (lr & 7)) << 3);
  const int va  = lr * 128 + ((lg ^ (lr & 15)) << 3);
  const int va1 = va ^ 32, va2 = va ^ 64, va3 = va ^ 96;

  const __hip_bfloat16* gk[4];
  const __hip_bfloat16* gv[4];
  __hip_bfloat16* lk[4];
  __hip_bfloat16* lv[4];
#pragma unroll
  for (int it = 0; it < 4; ++it) {
    int e = it * 2048 + tid * 8;
    int rowk = e >> 6;
    int lcolk = ((((e >> 3) & 7) ^ (rowk & 7)) << 3);
    gk[it] = Kp + (size_t)rowk * 64 + lcolk;
    lk[it] = &Klds[e];
    int rowv = e >> 7;
    int lcolv = ((((e >> 3) & 15) ^ (rowv & 15)) << 3);
    gv[it] = Vp + (size_t)rowv * TT + lcolv;
    lv[it] = &Vtlds[e];
  }

  const int kmaxwA = q0A + w * 16 + 15;
  const int kmaxwB = q0B + w * 16 + 15;
  const int qmA = qrowA - lg * 4;
  const int qmB = qrowB - lg * 4;
  const int nblk = (q0B + 63) / 128 + 1;
  for (int blk = 0; blk < nblk; ++blk) {
    const int kv0 = blk * 128;
#pragma unroll
    for (int it = 0; it < 4; ++it) {
      gl_lds16(gk[it], lk[it]);
      gk[it] += 128 * 64;
    }
#pragma unroll
    for (int it = 0; it < 4; ++it) {
      gl_lds16(gv[it], lv[it]);
      gv[it] += 128;
    }
    __syncthreads();
    if (kv0 <= q0A + 63)
      attn_chunks(Klds, Vtlds, ka, va, va1, va2, va3, kv0, kmaxwA, qmA, qfA0, qfA1, accA, lA);
    attn_chunks(Klds, Vtlds, ka, va, va1, va2, va3, kv0, kmaxwB, qmB, qfB0, qfB1, accB, lB);
    __syncthreads();
  }
  __hip_bfloat16* Ylds = Klds + w * 1024;
  store_tile(Ylds, accA, lA, q0A, w, l, lr, lg, bh, Y);
  store_tile(Ylds, accB, lB, q0B, w, l, lr, lg, bh, Y);
}

// ---------------- launch ----------------
extern "C" void kernel_launch(void* const* d_in, const int* in_sizes, int n_in,
                              void* d_out, int out_size, void* d_ws, size_t ws_size,
                              hipStream_t stream) {
  const float* x     = (const float*)d_in[0];
  const float* Wqkv  = (const float*)d_in[1];
  const float* bqkv  = (const float*)d_in[2];
  const float* Wproj = (const float*)d_in[3];
  const float* bproj = (const float*)d_in[4];

  char* ws = (char*)d_ws;
  size_t off = 0;
  auto alloc = [&](size_t bytes) {
    char* p = ws + off;
    off += (bytes + 255) & ~(size_t)255;
    return p;
  };
  __hip_bfloat16* xb    = (__hip_bfloat16*)alloc((size_t)MTOT * 1024 * 2);
  __hip_bfloat16* wqkvT = (__hip_bfloat16*)alloc((size_t)3072 * 1024 * 2);
  __hip_bfloat16* wpT   = (__hip_bfloat16*)alloc((size_t)1024 * 1024 * 2);
  __hip_bfloat16* Qb    = (__hip_bfloat16*)alloc((size_t)64 * TT * 64 * 2);
  __hip_bfloat16* Kb    = (__hip_bfloat16*)alloc((size_t)64 * TT * 64 * 2);
  __hip_bfloat16* Vtb   = (__hip_bfloat16*)alloc((size_t)64 * TT * 64 * 2);
  __hip_bfloat16* Yb    = (__hip_bfloat16*)alloc((size_t)MTOT * 1024 * 2);

  k_cvt<<<(MTOT * 1024 / 8 + 255) / 256, 256, 0, stream>>>(x, xb, MTOT * 1024 / 8);
  k_transpose_cvt<<<dim3(3072 / 32, 1024 / 32), 256, 0, stream>>>(Wqkv, wqkvT, 1024, 3072);
  k_transpose_cvt<<<dim3(1024 / 32, 1024 / 32), 256, 0, stream>>>(Wproj, wpT, 1024, 1024);
  k_gemm256<<<dim3(32, 12), 512, 0, stream>>>(xb, wqkvT, bqkv, Qb, Kb, Vtb);
  k_flash<<<16 * 64, 256, 0, stream>>>(Qb, Kb, Vtb, Yb);
  k_gemm<<<dim3(64, 8), 256, 0, stream>>>(Yb, wpT, bproj, (float*)d_out);
}

// Round 5
// 178.354 us; speedup vs baseline: 1.0930x; 1.0930x over previous
//
#include <hip/hip_runtime.h>
#include <hip/hip_bf16.h>
#include <cstdint>
#include <math.h>

// Problem constants
#define DM   1024
#define NH   16
#define DH   64
#define BB   4
#define TT   2048
#define MTOT (BB*TT)   // 8192 rows

using short8 = __attribute__((ext_vector_type(8))) short;  // 8 bf16 (4 VGPRs)
using f32x4  = __attribute__((ext_vector_type(4))) float;

__device__ __forceinline__ f32x4 mfma16(short8 a, short8 b, f32x4 c) {
  return __builtin_amdgcn_mfma_f32_16x16x32_bf16(a, b, c, 0, 0, 0);
}

typedef const __attribute__((address_space(1))) unsigned int* as1_u32p;
typedef __attribute__((address_space(3))) unsigned int*       as3_u32p;

// async global->LDS, 16B per lane; LDS dest = wave-uniform base + lane*16 (linear)
__device__ __forceinline__ void gl_lds16(const void* g, void* l) {
  __builtin_amdgcn_global_load_lds(
      (as1_u32p)(reinterpret_cast<uintptr_t>(g)),
      (as3_u32p)((unsigned int)(reinterpret_cast<uintptr_t>(l))),
      16, 0, 0);
}

// XOR swizzle for tiles with 64-elem (128B) rows: 8 slots of 8 bf16; slot ^= row&7
__device__ __forceinline__ int swz64(int row, int col) {
  return row*64 + ((((col >> 3) ^ (row & 7)) << 3) | (col & 7));
}

__device__ __forceinline__ unsigned pkbf(float a, float b) {
  __hip_bfloat162 h = __float22bfloat162_rn(make_float2(a, b)); // x=lo, y=hi
  return *reinterpret_cast<unsigned*>(&h);
}

// ---------------- fp32 -> bf16 copy convert ----------------
__global__ __launch_bounds__(256) void k_cvt(const float* __restrict__ in,
                                             __hip_bfloat16* __restrict__ out, int n8) {
  int i = blockIdx.x * 256 + threadIdx.x;
  if (i >= n8) return;
  const float* p = in + (size_t)i * 8;
  short8 o;
#pragma unroll
  for (int j = 0; j < 8; ++j) {
    __hip_bfloat16 h = __float2bfloat16(p[j]);
    o[j] = *reinterpret_cast<short*>(&h);
  }
  *reinterpret_cast<short8*>(out + (size_t)i * 8) = o;
}

// ---------------- W [K][N] fp32 -> Wt [N][K] bf16 (tiled transpose) ----------------
__global__ __launch_bounds__(256) void k_transpose_cvt(const float* __restrict__ W,
                                                       __hip_bfloat16* __restrict__ Wt,
                                                       int K, int N) {
  __shared__ float tbuf[32][33];
  const int n0 = blockIdx.x * 32, k0 = blockIdx.y * 32;
  const int tx = threadIdx.x & 31, ty = threadIdx.x >> 5;
#pragma unroll
  for (int i = 0; i < 4; ++i)
    tbuf[ty + i*8][tx] = W[(size_t)(k0 + ty + i*8) * N + n0 + tx];
  __syncthreads();
#pragma unroll
  for (int i = 0; i < 4; ++i)
    Wt[(size_t)(n0 + ty + i*8) * K + k0 + tx] = __float2bfloat16(tbuf[tx][ty + i*8]);
}

// ---------------- 128x128 bf16 GEMM, A[M][1024] @ Bt[N][1024]^T + bias ----------------
// EPI=0: LDS-bounce epilogue -> coalesced stores to Q (pre-scaled by 0.125*log2e),
//        K, and Vt (V transposed through wave-private LDS region).
// EPI=1: write fp32 out[M][1024]
template <int EPI>
__global__ __launch_bounds__(256) void k_gemm(const __hip_bfloat16* __restrict__ A,
                                              const __hip_bfloat16* __restrict__ Bt,
                                              const float* __restrict__ bias,
                                              float* __restrict__ outF,
                                              __hip_bfloat16* __restrict__ Qb,
                                              __hip_bfloat16* __restrict__ Kb,
                                              __hip_bfloat16* __restrict__ Vtb) {
  __shared__ __hip_bfloat16 As[128 * 64];
  __shared__ __hip_bfloat16 Bs[128 * 64];
  const int tid = threadIdx.x;
  const int l = tid & 63, w = tid >> 6;
  const int lr = l & 15, lg = l >> 4;
  const int wr = w >> 1, wc = w & 1;
  const int m0 = blockIdx.x * 128, n0 = blockIdx.y * 128;
  f32x4 acc[4][4] = {};
  for (int k0 = 0; k0 < 1024; k0 += 64) {
#pragma unroll
    for (int it = 0; it < 4; ++it) {      // stage A tile (pre-swizzled source)
      int e = it * 2048 + tid * 8;
      int row = e >> 6;
      int lcol = ((((e >> 3) & 7) ^ (row & 7)) << 3);
      gl_lds16(A + (size_t)(m0 + row) * 1024 + k0 + lcol, &As[e]);
    }
#pragma unroll
    for (int it = 0; it < 4; ++it) {      // stage Bt tile
      int e = it * 2048 + tid * 8;
      int row = e >> 6;
      int lcol = ((((e >> 3) & 7) ^ (row & 7)) << 3);
      gl_lds16(Bt + (size_t)(n0 + row) * 1024 + k0 + lcol, &Bs[e]);
    }
    __syncthreads();
#pragma unroll
    for (int ks = 0; ks < 2; ++ks) {
      short8 af[4], bf[4];
#pragma unroll
      for (int m = 0; m < 4; ++m)
        af[m] = *reinterpret_cast<const short8*>(&As[swz64(wr*64 + m*16 + lr, ks*32 + lg*8)]);
#pragma unroll
      for (int n = 0; n < 4; ++n)
        bf[n] = *reinterpret_cast<const short8*>(&Bs[swz64(wc*64 + n*16 + lr, ks*32 + lg*8)]);
#pragma unroll
      for (int m = 0; m < 4; ++m)
#pragma unroll
        for (int n = 0; n < 4; ++n)
          acc[m][n] = mfma16(af[m], bf[n], acc[m][n]);
    }
    __syncthreads();
  }

  if (EPI == 0) {
    // ---- LDS-bounce epilogue: wave-private 64x64 region, coalesced stores ----
    __hip_bfloat16* reg = (w < 2) ? &As[w * 4096] : &Bs[(w - 2) * 4096];
    const int colbase = n0 + wc * 64;        // wave-uniform: one head, one of Q/K/V
    const int which = colbase >> 10;
    const int hh = (colbase >> 6) & 15;
    const float qs = 0.18033688011112042f;   // 0.125 * log2(e) folded into Q
    // step 1: acc (+bias, scale) -> region; V-waves write transposed
#pragma unroll
    for (int n = 0; n < 4; ++n) {
      const int lc = n * 16 + lr;
      const float bv = bias[colbase + lc];
#pragma unroll
      for (int m = 0; m < 4; ++m) {
#pragma unroll
        for (int r = 0; r < 4; ++r) {
          const int lrow = m * 16 + lg * 4 + r;
          float v = acc[m][n][r] + bv;
          if (which == 0) v *= qs;
          const __hip_bfloat16 hv = __float2bfloat16(v);
          if (which == 2) reg[swz64(lc, lrow)] = hv;
          else            reg[swz64(lrow, lc)] = hv;
        }
      }
    }
    // step 2: coalesced stores (region is wave-private -> no barrier)
    const int rowbase = m0 + wr * 64;        // t-range start (64 rows)
    const int b = rowbase >> 11;             // uniform per wave
    const size_t bh = (size_t)b * 16 + hh;
    const int g = l >> 2, i = l & 3;
    if (which < 2) {
      __hip_bfloat16* base = (which == 0) ? Qb : Kb;
#pragma unroll
      for (int j = 0; j < 4; ++j) {
        const int lrow = j * 16 + g;
        const int t = (rowbase & 2047) + lrow;
        __hip_bfloat16* dst = base + (bh * TT + t) * 64 + i * 16;
        short8 y0 = *reinterpret_cast<const short8*>(&reg[swz64(lrow, i * 16)]);
        short8 y1 = *reinterpret_cast<const short8*>(&reg[swz64(lrow, i * 16 + 8)]);
        *reinterpret_cast<short8*>(dst) = y0;
        *reinterpret_cast<short8*>(dst + 8) = y1;
      }
    } else {
#pragma unroll
      for (int j = 0; j < 4; ++j) {
        const int dd = j * 16 + g;
        const int t = (rowbase & 2047) + i * 16;
        __hip_bfloat16* dst = Vtb + (bh * 64 + dd) * TT + t;
        short8 y0 = *reinterpret_cast<const short8*>(&reg[swz64(dd, i * 16)]);
        short8 y1 = *reinterpret_cast<const short8*>(&reg[swz64(dd, i * 16 + 8)]);
        *reinterpret_cast<short8*>(dst) = y0;
        *reinterpret_cast<short8*>(dst + 8) = y1;
      }
    }
  } else {
#pragma unroll
    for (int n = 0; n < 4; ++n) {
      const int col = n0 + wc*64 + n*16 + lr;
      const float bv = bias[col];
#pragma unroll
      for (int m = 0; m < 4; ++m)
#pragma unroll
        for (int r = 0; r < 4; ++r) {
          const int row = m0 + wr*64 + m*16 + lg*4 + r;
          outF[(size_t)row * 1024 + col] = acc[m][n][r] + bv;
        }
    }
  }
}

// ---------------- causal flash attention (paired q-tiles, fixed-max softmax) ----------------
// Block handles q-tiles {p, 31-p} (uniform work), shares K/V staging.
// Swapped QK^T: S^T = mfma(K, Q) -> lane holds q = lane&15, 4 keys per reg.
// Softmax in exp2 domain with FIXED max m=0 (logits bounded ~8 in log2 units -> no overflow;
// softmax is scale-invariant so result identical up to f32 rounding).
// All LDS read addresses precomputed: K-frags linear in kc, V-frags base^kc (XOR swizzle).
__device__ __forceinline__ void attn_chunks(const __hip_bfloat16* __restrict__ Klds,
                                            const __hip_bfloat16* __restrict__ Vtlds,
                                            int ka, int va0, int va1, int va2, int va3,
                                            int kv0, int kmaxw, int qm,
                                            short8 qf0, short8 qf1,
                                            f32x4 (&acc)[4], float& lrun) {
  const int vak[4] = {va0, va1, va2, va3};
#pragma unroll
  for (int kci = 0; kci < 4; ++kci) {
    const int kbase = kv0 + kci * 32;
    if (kbase > kmaxw) break;          // wave-uniform causal skip
    f32x4 s0 = {}, s1 = {};
    {
      const int kb = ka + kci * 2048;
      short8 kf00 = *reinterpret_cast<const short8*>(&Klds[kb]);
      short8 kf10 = *reinterpret_cast<const short8*>(&Klds[kb + 1024]);
      short8 kf01 = *reinterpret_cast<const short8*>(&Klds[kb ^ 32]);
      short8 kf11 = *reinterpret_cast<const short8*>(&Klds[(kb + 1024) ^ 32]);
      s0 = mfma16(kf00, qf0, s0);
      s1 = mfma16(kf10, qf0, s1);
      s0 = mfma16(kf01, qf1, s0);
      s1 = mfma16(kf11, qf1, s1);
    }
    if (kbase + 31 > kmaxw - 15) {     // diagonal chunk: per-element causal mask
#pragma unroll
      for (int r = 0; r < 4; ++r) {
        if (kbase + r > qm)      s0[r] = -INFINITY;
        if (kbase + 16 + r > qm) s1[r] = -INFINITY;
      }
    }
    float p0 = __builtin_amdgcn_exp2f(s0[0]), p1 = __builtin_amdgcn_exp2f(s0[1]);
    float p2 = __builtin_amdgcn_exp2f(s0[2]), p3 = __builtin_amdgcn_exp2f(s0[3]);
    float p4 = __builtin_amdgcn_exp2f(s1[0]), p5 = __builtin_amdgcn_exp2f(s1[1]);
    float p6 = __builtin_amdgcn_exp2f(s1[2]), p7 = __builtin_amdgcn_exp2f(s1[3]);
    lrun += ((p0 + p1) + (p2 + p3)) + ((p4 + p5) + (p6 + p7));
    unsigned u0 = pkbf(p0, p1);
    unsigned u1 = pkbf(p2, p3);
    unsigned u2 = pkbf(p4, p5);
    unsigned u3 = pkbf(p6, p7);
    const int l = threadIdx.x & 63;
    const int lr = l & 15, lg = l >> 4;
    const int sa = (((lg & 1) << 1) << 4) + lr;
    const int sb = sa + 16;
    unsigned va_0 = (unsigned)__shfl((int)u0, sa), va_1 = (unsigned)__shfl((int)u1, sa);
    unsigned va_2 = (unsigned)__shfl((int)u2, sa), va_3 = (unsigned)__shfl((int)u3, sa);
    unsigned vb_0 = (unsigned)__shfl((int)u0, sb), vb_1 = (unsigned)__shfl((int)u1, sb);
    unsigned vb_2 = (unsigned)__shfl((int)u2, sb), vb_3 = (unsigned)__shfl((int)u3, sb);
    const bool hi = lg >= 2;
    union { unsigned u[4]; short8 s; } pw;
    pw.u[0] = hi ? va_2 : va_0;
    pw.u[1] = hi ? va_3 : va_1;
    pw.u[2] = hi ? vb_2 : vb_0;
    pw.u[3] = hi ? vb_3 : vb_1;
    const short8 pf = pw.s;
    const int vb = vak[kci];
    short8 v0 = *reinterpret_cast<const short8*>(&Vtlds[vb]);
    short8 v1 = *reinterpret_cast<const short8*>(&Vtlds[vb + 2048]);
    short8 v2 = *reinterpret_cast<const short8*>(&Vtlds[vb + 4096]);
    short8 v3 = *reinterpret_cast<const short8*>(&Vtlds[vb + 6144]);
    acc[0] = mfma16(v0, pf, acc[0]);
    acc[1] = mfma16(v1, pf, acc[1]);
    acc[2] = mfma16(v2, pf, acc[2]);
    acc[3] = mfma16(v3, pf, acc[3]);
  }
}

__device__ __forceinline__ void store_tile(__hip_bfloat16* Ylds, f32x4 (&acc)[4],
                                           float lrun, int q0, int w, int l,
                                           int lr, int lg, int bh,
                                           __hip_bfloat16* __restrict__ Y) {
  lrun += __shfl_xor(lrun, 16);
  lrun += __shfl_xor(lrun, 32);
  const float inv = 1.f / lrun;
#pragma unroll
  for (int nb = 0; nb < 4; ++nb) {
#pragma unroll
    for (int r = 0; r < 4; ++r) {
      const int d = nb * 16 + lg * 4 + r;
      Ylds[swz64(lr, d)] = __float2bfloat16(acc[nb][r] * inv);
    }
  }
  const int rr = l >> 2, part = l & 3;
  const int trow = q0 + w * 16 + rr;
  const int b = bh >> 4, h = bh & 15;
  short8 y0 = *reinterpret_cast<const short8*>(&Ylds[swz64(rr, part * 16)]);
  short8 y1 = *reinterpret_cast<const short8*>(&Ylds[swz64(rr, part * 16 + 8)]);
  __hip_bfloat16* dst = Y + ((size_t)b * TT + trow) * 1024 + h * 64 + part * 16;
  *reinterpret_cast<short8*>(dst) = y0;
  *reinterpret_cast<short8*>(dst + 8) = y1;
}

__global__ __launch_bounds__(256, 4) void k_flash(const __hip_bfloat16* __restrict__ Qb,
                                                  const __hip_bfloat16* __restrict__ Kb,
                                                  const __hip_bfloat16* __restrict__ Vtb,
                                                  __hip_bfloat16* __restrict__ Y) {
  __shared__ __hip_bfloat16 Klds[128 * 64];
  __shared__ __hip_bfloat16 Vtlds[64 * 128];
  const int tid = threadIdx.x;
  const int l = tid & 63, w = tid >> 6;
  const int lr = l & 15, lg = l >> 4;
  const int p  = blockIdx.x >> 6;       // pair index 0..15
  const int bh = blockIdx.x & 63;
  const int q0A = p * 64, q0B = (31 - p) * 64;
  const __hip_bfloat16* Qp = Qb + (size_t)bh * TT * 64;
  const __hip_bfloat16* Kp = Kb + (size_t)bh * TT * 64;
  const __hip_bfloat16* Vp = Vtb + (size_t)bh * 64 * TT;
  const int qrowA = q0A + w * 16 + lr;
  const int qrowB = q0B + w * 16 + lr;
  const short8 qfA0 = *reinterpret_cast<const short8*>(Qp + (size_t)qrowA * 64 + lg * 8);
  const short8 qfA1 = *reinterpret_cast<const short8*>(Qp + (size_t)qrowA * 64 + 32 + lg * 8);
  const short8 qfB0 = *reinterpret_cast<const short8*>(Qp + (size_t)qrowB * 64 + lg * 8);
  const short8 qfB1 = *reinterpret_cast<const short8*>(Qp + (size_t)qrowB * 64 + 32 + lg * 8);
  f32x4 accA[4] = {}, accB[4] = {};
  float lA = 0.f, lB = 0.f;

  const int ka  = lr * 64 + ((lg ^ (lr & 7)) << 3);
  const int va  = lr * 128 + ((lg ^ (lr & 15)) << 3);
  const int va1 = va ^ 32, va2 = va ^ 64, va3 = va ^ 96;

  const __hip_bfloat16* gk[4];
  const __hip_bfloat16* gv[4];
  __hip_bfloat16* lk[4];
  __hip_bfloat16* lv[4];
#pragma unroll
  for (int it = 0; it < 4; ++it) {
    int e = it * 2048 + tid * 8;
    int rowk = e >> 6;
    int lcolk = ((((e >> 3) & 7) ^ (rowk & 7)) << 3);
    gk[it] = Kp + (size_t)rowk * 64 + lcolk;
    lk[it] = &Klds[e];
    int rowv = e >> 7;
    int lcolv = ((((e >> 3) & 15) ^ (rowv & 15)) << 3);
    gv[it] = Vp + (size_t)rowv * TT + lcolv;
    lv[it] = &Vtlds[e];
  }

  const int kmaxwA = q0A + w * 16 + 15;
  const int kmaxwB = q0B + w * 16 + 15;
  const int qmA = qrowA - lg * 4;
  const int qmB = qrowB - lg * 4;
  const int nblk = (q0B + 63) / 128 + 1;
  for (int blk = 0; blk < nblk; ++blk) {
    const int kv0 = blk * 128;
#pragma unroll
    for (int it = 0; it < 4; ++it) {
      gl_lds16(gk[it], lk[it]);
      gk[it] += 128 * 64;
    }
#pragma unroll
    for (int it = 0; it < 4; ++it) {
      gl_lds16(gv[it], lv[it]);
      gv[it] += 128;
    }
    __syncthreads();
    if (kv0 <= q0A + 63)
      attn_chunks(Klds, Vtlds, ka, va, va1, va2, va3, kv0, kmaxwA, qmA, qfA0, qfA1, accA, lA);
    attn_chunks(Klds, Vtlds, ka, va, va1, va2, va3, kv0, kmaxwB, qmB, qfB0, qfB1, accB, lB);
    __syncthreads();
  }
  __hip_bfloat16* Ylds = Klds + w * 1024;
  store_tile(Ylds, accA, lA, q0A, w, l, lr, lg, bh, Y);
  store_tile(Ylds, accB, lB, q0B, w, l, lr, lg, bh, Y);
}

// ---------------- launch ----------------
extern "C" void kernel_launch(void* const* d_in, const int* in_sizes, int n_in,
                              void* d_out, int out_size, void* d_ws, size_t ws_size,
                              hipStream_t stream) {
  const float* x     = (const float*)d_in[0];
  const float* Wqkv  = (const float*)d_in[1];
  const float* bqkv  = (const float*)d_in[2];
  const float* Wproj = (const float*)d_in[3];
  const float* bproj = (const float*)d_in[4];

  char* ws = (char*)d_ws;
  size_t off = 0;
  auto alloc = [&](size_t bytes) {
    char* p = ws + off;
    off += (bytes + 255) & ~(size_t)255;
    return p;
  };
  __hip_bfloat16* xb    = (__hip_bfloat16*)alloc((size_t)MTOT * 1024 * 2);
  __hip_bfloat16* wqkvT = (__hip_bfloat16*)alloc((size_t)3072 * 1024 * 2);
  __hip_bfloat16* wpT   = (__hip_bfloat16*)alloc((size_t)1024 * 1024 * 2);
  __hip_bfloat16* Qb    = (__hip_bfloat16*)alloc((size_t)64 * TT * 64 * 2);
  __hip_bfloat16* Kb    = (__hip_bfloat16*)alloc((size_t)64 * TT * 64 * 2);
  __hip_bfloat16* Vtb   = (__hip_bfloat16*)alloc((size_t)64 * TT * 64 * 2);
  __hip_bfloat16* Yb    = (__hip_bfloat16*)alloc((size_t)MTOT * 1024 * 2);

  k_cvt<<<(MTOT * 1024 / 8 + 255) / 256, 256, 0, stream>>>(x, xb, MTOT * 1024 / 8);
  k_transpose_cvt<<<dim3(3072 / 32, 1024 / 32), 256, 0, stream>>>(Wqkv, wqkvT, 1024, 3072);
  k_transpose_cvt<<<dim3(1024 / 32, 1024 / 32), 256, 0, stream>>>(Wproj, wpT, 1024, 1024);
  k_gemm<0><<<dim3(64, 24), 256, 0, stream>>>(xb, wqkvT, bqkv, nullptr, Qb, Kb, Vtb);
  k_flash<<<16 * 64, 256, 0, stream>>>(Qb, Kb, Vtb, Yb);
  k_gemm<1><<<dim3(64, 8), 256, 0, stream>>>(Yb, wpT, bproj, (float*)d_out,
                                             nullptr, nullptr, nullptr);
}

// Round 6
// 168.000 us; speedup vs baseline: 1.1603x; 1.0616x over previous
//
#include <hip/hip_runtime.h>
#include <hip/hip_bf16.h>
#include <cstdint>
#include <math.h>

// Problem constants
#define DM   1024
#define NH   16
#define DH   64
#define BB   4
#define TT   2048
#define MTOT (BB*TT)   // 8192 rows

using short8 = __attribute__((ext_vector_type(8))) short;  // 8 bf16 (4 VGPRs)
using f32x4  = __attribute__((ext_vector_type(4))) float;

__device__ __forceinline__ f32x4 mfma16(short8 a, short8 b, f32x4 c) {
  return __builtin_amdgcn_mfma_f32_16x16x32_bf16(a, b, c, 0, 0, 0);
}

typedef const __attribute__((address_space(1))) unsigned int* as1_u32p;
typedef __attribute__((address_space(3))) unsigned int*       as3_u32p;

// async global->LDS, 16B per lane; LDS dest = wave-uniform base + lane*16 (linear)
__device__ __forceinline__ void gl_lds16(const void* g, void* l) {
  __builtin_amdgcn_global_load_lds(
      (as1_u32p)(reinterpret_cast<uintptr_t>(g)),
      (as3_u32p)((unsigned int)(reinterpret_cast<uintptr_t>(l))),
      16, 0, 0);
}

// XOR swizzle for tiles with 64-elem (128B) rows: 8 slots of 8 bf16; slot ^= row&7
__device__ __forceinline__ int swz64(int row, int col) {
  return row*64 + ((((col >> 3) ^ (row & 7)) << 3) | (col & 7));
}

__device__ __forceinline__ unsigned pkbf(float a, float b) {
  __hip_bfloat162 h = __float22bfloat162_rn(make_float2(a, b)); // x=lo, y=hi
  return *reinterpret_cast<unsigned*>(&h);
}

// inline-asm LDS reads (opaque to alias analysis: no compiler-inserted vmcnt drains)
__device__ __forceinline__ short8 ldsr_o0(unsigned a) {
  short8 r; asm volatile("ds_read_b128 %0, %1" : "=v"(r) : "v"(a)); return r;
}
__device__ __forceinline__ short8 ldsr_o1(unsigned a) {
  short8 r; asm volatile("ds_read_b128 %0, %1 offset:2048" : "=v"(r) : "v"(a)); return r;
}
__device__ __forceinline__ short8 ldsr_o2(unsigned a) {
  short8 r; asm volatile("ds_read_b128 %0, %1 offset:4096" : "=v"(r) : "v"(a)); return r;
}
__device__ __forceinline__ short8 ldsr_o3(unsigned a) {
  short8 r; asm volatile("ds_read_b128 %0, %1 offset:6144" : "=v"(r) : "v"(a)); return r;
}

#define LGKM0  do { asm volatile("s_waitcnt lgkmcnt(0)"); __builtin_amdgcn_sched_barrier(0); } while(0)
#define VMCNT6 do { __builtin_amdgcn_sched_barrier(0); asm volatile("s_waitcnt vmcnt(6)"); __builtin_amdgcn_sched_barrier(0); } while(0)
#define VMCNT0 do { __builtin_amdgcn_sched_barrier(0); asm volatile("s_waitcnt vmcnt(0)"); __builtin_amdgcn_sched_barrier(0); } while(0)
#define BARRIER do { __builtin_amdgcn_s_barrier(); __builtin_amdgcn_sched_barrier(0); } while(0)

// ---------------- fp32 -> bf16 copy convert ----------------
__global__ __launch_bounds__(256) void k_cvt(const float* __restrict__ in,
                                             __hip_bfloat16* __restrict__ out, int n8) {
  int i = blockIdx.x * 256 + threadIdx.x;
  if (i >= n8) return;
  const float* p = in + (size_t)i * 8;
  short8 o;
#pragma unroll
  for (int j = 0; j < 8; ++j) {
    __hip_bfloat16 h = __float2bfloat16(p[j]);
    o[j] = *reinterpret_cast<short*>(&h);
  }
  *reinterpret_cast<short8*>(out + (size_t)i * 8) = o;
}

// ---------------- W [K][N] fp32 -> Wt [N][K] bf16 (tiled transpose) ----------------
__global__ __launch_bounds__(256) void k_transpose_cvt(const float* __restrict__ W,
                                                       __hip_bfloat16* __restrict__ Wt,
                                                       int K, int N) {
  __shared__ float tbuf[32][33];
  const int n0 = blockIdx.x * 32, k0 = blockIdx.y * 32;
  const int tx = threadIdx.x & 31, ty = threadIdx.x >> 5;
#pragma unroll
  for (int i = 0; i < 4; ++i)
    tbuf[ty + i*8][tx] = W[(size_t)(k0 + ty + i*8) * N + n0 + tx];
  __syncthreads();
#pragma unroll
  for (int i = 0; i < 4; ++i)
    Wt[(size_t)(n0 + ty + i*8) * K + k0 + tx] = __float2bfloat16(tbuf[tx][ty + i*8]);
}

// ---------------- 256x128 triple-buffered deep-pipeline QKV GEMM ----------------
// 512 threads / 8 waves (4m x 2n), per-wave 64x64 output. BK=64, 16 K-tiles.
// Stage tile t+2 while computing tile t (3 LDS slots -> WAR-free by construction).
// One s_barrier + one counted vmcnt(6) per K-tile; inline-asm ds_read_b128.
__global__ __launch_bounds__(512, 2) void k_gemm2(const __hip_bfloat16* __restrict__ A,
                                                  const __hip_bfloat16* __restrict__ Bt,
                                                  const float* __restrict__ bias,
                                                  __hip_bfloat16* __restrict__ Qb,
                                                  __hip_bfloat16* __restrict__ Kb,
                                                  __hip_bfloat16* __restrict__ Vtb) {
  __shared__ __hip_bfloat16 As[3][256 * 64];
  __shared__ __hip_bfloat16 Bs[3][128 * 64];
  const int tid = threadIdx.x;
  const int l = tid & 63, w = tid >> 6;
  const int lr = l & 15, lg = l >> 4;
  const int wm = w >> 1, wn = w & 1;
  const int m0 = blockIdx.x * 256, n0 = blockIdx.y * 128;

  // staging constants (pre-swizzled source, linear LDS dest)
  const int srow = tid >> 3;                               // 0..63
  const int scol = (((tid & 7) ^ (srow & 7)) << 3);
  const size_t aoffs = (size_t)(m0 + srow) * 1024 + scol;  // + round*64 rows + k0
  const size_t boffs = (size_t)(n0 + srow) * 1024 + scol;
  const int ldst = tid * 8;

  auto stage = [&](int t, int s) {
    const int k0 = t * 64;
    __hip_bfloat16* as_ = &As[s][0];
    __hip_bfloat16* bs_ = &Bs[s][0];
#pragma unroll
    for (int rd = 0; rd < 4; ++rd)
      gl_lds16(A + aoffs + (size_t)rd * 65536 + k0, as_ + rd * 4096 + ldst);
#pragma unroll
    for (int rd = 0; rd < 2; ++rd)
      gl_lds16(Bt + boffs + (size_t)rd * 65536 + k0, bs_ + rd * 4096 + ldst);
  };

  // fragment read base addresses (LDS byte addresses)
  const unsigned asLds = (unsigned)(uintptr_t)&As[0][0];
  const unsigned bsLds = (unsigned)(uintptr_t)&Bs[0][0];
  const unsigned aBase = asLds + 2u * ((wm*64 + lr) * 64 + ((lg ^ (lr & 7)) << 3));
  const unsigned bBase = bsLds + 2u * ((wn*64 + lr) * 64 + ((lg ^ (lr & 7)) << 3));

  // prologue: stage tiles 0,1; wait tile0 complete (tile1's 6 loads remain)
  stage(0, 0);
  stage(1, 1);
  VMCNT6;
  BARRIER;

  f32x4 acc[4][4] = {};
  short8 a_[4][2], b_[2][2];

#pragma unroll
  for (int t = 0; t < 16; ++t) {
    const int s = t % 3;
    const unsigned aB0 = aBase + (unsigned)s * 32768u;
    const unsigned aB1 = aB0 ^ 64u;
    const unsigned bB0 = bBase + (unsigned)s * 16384u;
    const unsigned bB1 = bB0 ^ 64u;
    // issue next+1 tile's staging (slot (t+2)%3 was freed by the previous barrier)
    if (t + 2 < 16) stage(t + 2, (t + 2) % 3);
    // phase 0: read A frags + B n01, MFMA n=0,1
    a_[0][0] = ldsr_o0(aB0); a_[1][0] = ldsr_o1(aB0); a_[2][0] = ldsr_o2(aB0); a_[3][0] = ldsr_o3(aB0);
    a_[0][1] = ldsr_o0(aB1); a_[1][1] = ldsr_o1(aB1); a_[2][1] = ldsr_o2(aB1); a_[3][1] = ldsr_o3(aB1);
    b_[0][0] = ldsr_o0(bB0); b_[1][0] = ldsr_o1(bB0);
    b_[0][1] = ldsr_o0(bB1); b_[1][1] = ldsr_o1(bB1);
    LGKM0;
    __builtin_amdgcn_s_setprio(1);
#pragma unroll
    for (int m = 0; m < 4; ++m)
#pragma unroll
      for (int n = 0; n < 2; ++n)
#pragma unroll
        for (int ks = 0; ks < 2; ++ks)
          acc[m][n] = mfma16(a_[m][ks], b_[n][ks], acc[m][n]);
    __builtin_amdgcn_s_setprio(0);
    // phase 1: read B n23, MFMA n=2,3
    b_[0][0] = ldsr_o2(bB0); b_[1][0] = ldsr_o3(bB0);
    b_[0][1] = ldsr_o2(bB1); b_[1][1] = ldsr_o3(bB1);
    LGKM0;
    __builtin_amdgcn_s_setprio(1);
#pragma unroll
    for (int m = 0; m < 4; ++m)
#pragma unroll
      for (int n = 0; n < 2; ++n)
#pragma unroll
        for (int ks = 0; ks < 2; ++ks)
          acc[m][n + 2] = mfma16(a_[m][ks], b_[n][ks], acc[m][n + 2]);
    __builtin_amdgcn_s_setprio(0);
    // boundary: retire tile t+1's loads, publish, free slot t%3
    if (t <= 13) { VMCNT6; }
    else if (t == 14) { VMCNT0; }
    BARRIER;
  }

  __syncthreads();
  // ---- LDS-bounce epilogue: wave-private 64x64 region, coalesced stores ----
  __hip_bfloat16* reg = &As[0][0] + w * 4096;
  const int colbase = n0 + wn * 64;          // wave-uniform: one head, one of Q/K/V
  const int which = colbase >> 10;
  const int hh = (colbase >> 6) & 15;
  const float qs = 0.18033688011112042f;     // 0.125 * log2(e) folded into Q
#pragma unroll
  for (int n = 0; n < 4; ++n) {
    const int lc = n * 16 + lr;
    const float bv = bias[colbase + lc];
#pragma unroll
    for (int m = 0; m < 4; ++m) {
#pragma unroll
      for (int r = 0; r < 4; ++r) {
        const int lrow = m * 16 + lg * 4 + r;
        float v = acc[m][n][r] + bv;
        if (which == 0) v *= qs;
        const __hip_bfloat16 hv = __float2bfloat16(v);
        if (which == 2) reg[swz64(lc, lrow)] = hv;
        else            reg[swz64(lrow, lc)] = hv;
      }
    }
  }
  const int rowbase = m0 + wm * 64;
  const int b = rowbase >> 11;
  const size_t bh = (size_t)b * 16 + hh;
  const int g = l >> 2, i = l & 3;
  if (which < 2) {
    __hip_bfloat16* base = (which == 0) ? Qb : Kb;
#pragma unroll
    for (int j = 0; j < 4; ++j) {
      const int lrow = j * 16 + g;
      const int t = (rowbase & 2047) + lrow;
      __hip_bfloat16* dst = base + (bh * TT + t) * 64 + i * 16;
      short8 y0 = *reinterpret_cast<const short8*>(&reg[swz64(lrow, i * 16)]);
      short8 y1 = *reinterpret_cast<const short8*>(&reg[swz64(lrow, i * 16 + 8)]);
      *reinterpret_cast<short8*>(dst) = y0;
      *reinterpret_cast<short8*>(dst + 8) = y1;
    }
  } else {
#pragma unroll
    for (int j = 0; j < 4; ++j) {
      const int dd = j * 16 + g;
      const int t = (rowbase & 2047) + i * 16;
      __hip_bfloat16* dst = Vtb + (bh * 64 + dd) * TT + t;
      short8 y0 = *reinterpret_cast<const short8*>(&reg[swz64(dd, i * 16)]);
      short8 y1 = *reinterpret_cast<const short8*>(&reg[swz64(dd, i * 16 + 8)]);
      *reinterpret_cast<short8*>(dst) = y0;
      *reinterpret_cast<short8*>(dst + 8) = y1;
    }
  }
}

// ---------------- 128x128 bf16 GEMM (proj): A[M][1024] @ Bt[N][1024]^T + bias -> fp32 ----------------
__global__ __launch_bounds__(256) void k_gemm(const __hip_bfloat16* __restrict__ A,
                                              const __hip_bfloat16* __restrict__ Bt,
                                              const float* __restrict__ bias,
                                              float* __restrict__ outF) {
  __shared__ __hip_bfloat16 As[128 * 64];
  __shared__ __hip_bfloat16 Bs[128 * 64];
  const int tid = threadIdx.x;
  const int l = tid & 63, w = tid >> 6;
  const int lr = l & 15, lg = l >> 4;
  const int wr = w >> 1, wc = w & 1;
  const int m0 = blockIdx.x * 128, n0 = blockIdx.y * 128;
  f32x4 acc[4][4] = {};
  for (int k0 = 0; k0 < 1024; k0 += 64) {
#pragma unroll
    for (int it = 0; it < 4; ++it) {
      int e = it * 2048 + tid * 8;
      int row = e >> 6;
      int lcol = ((((e >> 3) & 7) ^ (row & 7)) << 3);
      gl_lds16(A + (size_t)(m0 + row) * 1024 + k0 + lcol, &As[e]);
    }
#pragma unroll
    for (int it = 0; it < 4; ++it) {
      int e = it * 2048 + tid * 8;
      int row = e >> 6;
      int lcol = ((((e >> 3) & 7) ^ (row & 7)) << 3);
      gl_lds16(Bt + (size_t)(n0 + row) * 1024 + k0 + lcol, &Bs[e]);
    }
    __syncthreads();
#pragma unroll
    for (int ks = 0; ks < 2; ++ks) {
      short8 af[4], bf[4];
#pragma unroll
      for (int m = 0; m < 4; ++m)
        af[m] = *reinterpret_cast<const short8*>(&As[swz64(wr*64 + m*16 + lr, ks*32 + lg*8)]);
#pragma unroll
      for (int n = 0; n < 4; ++n)
        bf[n] = *reinterpret_cast<const short8*>(&Bs[swz64(wc*64 + n*16 + lr, ks*32 + lg*8)]);
#pragma unroll
      for (int m = 0; m < 4; ++m)
#pragma unroll
        for (int n = 0; n < 4; ++n)
          acc[m][n] = mfma16(af[m], bf[n], acc[m][n]);
    }
    __syncthreads();
  }
#pragma unroll
  for (int n = 0; n < 4; ++n) {
    const int col = n0 + wc*64 + n*16 + lr;
    const float bv = bias[col];
#pragma unroll
    for (int m = 0; m < 4; ++m)
#pragma unroll
      for (int r = 0; r < 4; ++r) {
        const int row = m0 + wr*64 + m*16 + lg*4 + r;
        outF[(size_t)row * 1024 + col] = acc[m][n][r] + bv;
      }
  }
}

// ---------------- causal flash attention (paired q-tiles, fixed-max softmax) ----------------
__device__ __forceinline__ void attn_chunks(const __hip_bfloat16* __restrict__ Klds,
                                            const __hip_bfloat16* __restrict__ Vtlds,
                                            int ka, int va0, int va1, int va2, int va3,
                                            int kv0, int kmaxw, int qm,
                                            short8 qf0, short8 qf1,
                                            f32x4 (&acc)[4], float& lrun) {
  const int vak[4] = {va0, va1, va2, va3};
#pragma unroll
  for (int kci = 0; kci < 4; ++kci) {
    const int kbase = kv0 + kci * 32;
    if (kbase > kmaxw) break;          // wave-uniform causal skip
    f32x4 s0 = {}, s1 = {};
    {
      const int kb = ka + kci * 2048;
      short8 kf00 = *reinterpret_cast<const short8*>(&Klds[kb]);
      short8 kf10 = *reinterpret_cast<const short8*>(&Klds[kb + 1024]);
      short8 kf01 = *reinterpret_cast<const short8*>(&Klds[kb ^ 32]);
      short8 kf11 = *reinterpret_cast<const short8*>(&Klds[(kb + 1024) ^ 32]);
      s0 = mfma16(kf00, qf0, s0);
      s1 = mfma16(kf10, qf0, s1);
      s0 = mfma16(kf01, qf1, s0);
      s1 = mfma16(kf11, qf1, s1);
    }
    if (kbase + 31 > kmaxw - 15) {     // diagonal chunk: per-element causal mask
#pragma unroll
      for (int r = 0; r < 4; ++r) {
        if (kbase + r > qm)      s0[r] = -INFINITY;
        if (kbase + 16 + r > qm) s1[r] = -INFINITY;
      }
    }
    float p0 = __builtin_amdgcn_exp2f(s0[0]), p1 = __builtin_amdgcn_exp2f(s0[1]);
    float p2 = __builtin_amdgcn_exp2f(s0[2]), p3 = __builtin_amdgcn_exp2f(s0[3]);
    float p4 = __builtin_amdgcn_exp2f(s1[0]), p5 = __builtin_amdgcn_exp2f(s1[1]);
    float p6 = __builtin_amdgcn_exp2f(s1[2]), p7 = __builtin_amdgcn_exp2f(s1[3]);
    lrun += ((p0 + p1) + (p2 + p3)) + ((p4 + p5) + (p6 + p7));
    unsigned u0 = pkbf(p0, p1);
    unsigned u1 = pkbf(p2, p3);
    unsigned u2 = pkbf(p4, p5);
    unsigned u3 = pkbf(p6, p7);
    const int l = threadIdx.x & 63;
    const int lr = l & 15, lg = l >> 4;
    const int sa = (((lg & 1) << 1) << 4) + lr;
    const int sb = sa + 16;
    unsigned va_0 = (unsigned)__shfl((int)u0, sa), va_1 = (unsigned)__shfl((int)u1, sa);
    unsigned va_2 = (unsigned)__shfl((int)u2, sa), va_3 = (unsigned)__shfl((int)u3, sa);
    unsigned vb_0 = (unsigned)__shfl((int)u0, sb), vb_1 = (unsigned)__shfl((int)u1, sb);
    unsigned vb_2 = (unsigned)__shfl((int)u2, sb), vb_3 = (unsigned)__shfl((int)u3, sb);
    const bool hi = lg >= 2;
    union { unsigned u[4]; short8 s; } pw;
    pw.u[0] = hi ? va_2 : va_0;
    pw.u[1] = hi ? va_3 : va_1;
    pw.u[2] = hi ? vb_2 : vb_0;
    pw.u[3] = hi ? vb_3 : vb_1;
    const short8 pf = pw.s;
    const int vb = vak[kci];
    short8 v0 = *reinterpret_cast<const short8*>(&Vtlds[vb]);
    short8 v1 = *reinterpret_cast<const short8*>(&Vtlds[vb + 2048]);
    short8 v2 = *reinterpret_cast<const short8*>(&Vtlds[vb + 4096]);
    short8 v3 = *reinterpret_cast<const short8*>(&Vtlds[vb + 6144]);
    acc[0] = mfma16(v0, pf, acc[0]);
    acc[1] = mfma16(v1, pf, acc[1]);
    acc[2] = mfma16(v2, pf, acc[2]);
    acc[3] = mfma16(v3, pf, acc[3]);
  }
}

__device__ __forceinline__ void store_tile(__hip_bfloat16* Ylds, f32x4 (&acc)[4],
                                           float lrun, int q0, int w, int l,
                                           int lr, int lg, int bh,
                                           __hip_bfloat16* __restrict__ Y) {
  lrun += __shfl_xor(lrun, 16);
  lrun += __shfl_xor(lrun, 32);
  const float inv = 1.f / lrun;
#pragma unroll
  for (int nb = 0; nb < 4; ++nb) {
#pragma unroll
    for (int r = 0; r < 4; ++r) {
      const int d = nb * 16 + lg * 4 + r;
      Ylds[swz64(lr, d)] = __float2bfloat16(acc[nb][r] * inv);
    }
  }
  const int rr = l >> 2, part = l & 3;
  const int trow = q0 + w * 16 + rr;
  const int b = bh >> 4, h = bh & 15;
  short8 y0 = *reinterpret_cast<const short8*>(&Ylds[swz64(rr, part * 16)]);
  short8 y1 = *reinterpret_cast<const short8*>(&Ylds[swz64(rr, part * 16 + 8)]);
  __hip_bfloat16* dst = Y + ((size_t)b * TT + trow) * 1024 + h * 64 + part * 16;
  *reinterpret_cast<short8*>(dst) = y0;
  *reinterpret_cast<short8*>(dst + 8) = y1;
}

__global__ __launch_bounds__(256, 4) void k_flash(const __hip_bfloat16* __restrict__ Qb,
                                                  const __hip_bfloat16* __restrict__ Kb,
                                                  const __hip_bfloat16* __restrict__ Vtb,
                                                  __hip_bfloat16* __restrict__ Y) {
  __shared__ __hip_bfloat16 Klds[128 * 64];
  __shared__ __hip_bfloat16 Vtlds[64 * 128];
  const int tid = threadIdx.x;
  const int l = tid & 63, w = tid >> 6;
  const int lr = l & 15, lg = l >> 4;
  const int p  = blockIdx.x >> 6;       // pair index 0..15
  const int bh = blockIdx.x & 63;
  const int q0A = p * 64, q0B = (31 - p) * 64;
  const __hip_bfloat16* Qp = Qb + (size_t)bh * TT * 64;
  const __hip_bfloat16* Kp = Kb + (size_t)bh * TT * 64;
  const __hip_bfloat16* Vp = Vtb + (size_t)bh * 64 * TT;
  const int qrowA = q0A + w * 16 + lr;
  const int qrowB = q0B + w * 16 + lr;
  const short8 qfA0 = *reinterpret_cast<const short8*>(Qp + (size_t)qrowA * 64 + lg * 8);
  const short8 qfA1 = *reinterpret_cast<const short8*>(Qp + (size_t)qrowA * 64 + 32 + lg * 8);
  const short8 qfB0 = *reinterpret_cast<const short8*>(Qp + (size_t)qrowB * 64 + lg * 8);
  const short8 qfB1 = *reinterpret_cast<const short8*>(Qp + (size_t)qrowB * 64 + 32 + lg * 8);
  f32x4 accA[4] = {}, accB[4] = {};
  float lA = 0.f, lB = 0.f;

  const int ka  = lr * 64 + ((lg ^ (lr & 7)) << 3);
  const int va  = lr * 128 + ((lg ^ (lr & 15)) << 3);
  const int va1 = va ^ 32, va2 = va ^ 64, va3 = va ^ 96;

  const __hip_bfloat16* gk[4];
  const __hip_bfloat16* gv[4];
  __hip_bfloat16* lk[4];
  __hip_bfloat16* lv[4];
#pragma unroll
  for (int it = 0; it < 4; ++it) {
    int e = it * 2048 + tid * 8;
    int rowk = e >> 6;
    int lcolk = ((((e >> 3) & 7) ^ (rowk & 7)) << 3);
    gk[it] = Kp + (size_t)rowk * 64 + lcolk;
    lk[it] = &Klds[e];
    int rowv = e >> 7;
    int lcolv = ((((e >> 3) & 15) ^ (rowv & 15)) << 3);
    gv[it] = Vp + (size_t)rowv * TT + lcolv;
    lv[it] = &Vtlds[e];
  }

  const int kmaxwA = q0A + w * 16 + 15;
  const int kmaxwB = q0B + w * 16 + 15;
  const int qmA = qrowA - lg * 4;
  const int qmB = qrowB - lg * 4;
  const int nblk = (q0B + 63) / 128 + 1;
  for (int blk = 0; blk < nblk; ++blk) {
    const int kv0 = blk * 128;
#pragma unroll
    for (int it = 0; it < 4; ++it) {
      gl_lds16(gk[it], lk[it]);
      gk[it] += 128 * 64;
    }
#pragma unroll
    for (int it = 0; it < 4; ++it) {
      gl_lds16(gv[it], lv[it]);
      gv[it] += 128;
    }
    __syncthreads();
    if (kv0 <= q0A + 63)
      attn_chunks(Klds, Vtlds, ka, va, va1, va2, va3, kv0, kmaxwA, qmA, qfA0, qfA1, accA, lA);
    attn_chunks(Klds, Vtlds, ka, va, va1, va2, va3, kv0, kmaxwB, qmB, qfB0, qfB1, accB, lB);
    __syncthreads();
  }
  __hip_bfloat16* Ylds = Klds + w * 1024;
  store_tile(Ylds, accA, lA, q0A, w, l, lr, lg, bh, Y);
  store_tile(Ylds, accB, lB, q0B, w, l, lr, lg, bh, Y);
}

// ---------------- launch ----------------
extern "C" void kernel_launch(void* const* d_in, const int* in_sizes, int n_in,
                              void* d_out, int out_size, void* d_ws, size_t ws_size,
                              hipStream_t stream) {
  const float* x     = (const float*)d_in[0];
  const float* Wqkv  = (const float*)d_in[1];
  const float* bqkv  = (const float*)d_in[2];
  const float* Wproj = (const float*)d_in[3];
  const float* bproj = (const float*)d_in[4];

  char* ws = (char*)d_ws;
  size_t off = 0;
  auto alloc = [&](size_t bytes) {
    char* p = ws + off;
    off += (bytes + 255) & ~(size_t)255;
    return p;
  };
  __hip_bfloat16* xb    = (__hip_bfloat16*)alloc((size_t)MTOT * 1024 * 2);
  __hip_bfloat16* wqkvT = (__hip_bfloat16*)alloc((size_t)3072 * 1024 * 2);
  __hip_bfloat16* wpT   = (__hip_bfloat16*)alloc((size_t)1024 * 1024 * 2);
  __hip_bfloat16* Qb    = (__hip_bfloat16*)alloc((size_t)64 * TT * 64 * 2);
  __hip_bfloat16* Kb    = (__hip_bfloat16*)alloc((size_t)64 * TT * 64 * 2);
  __hip_bfloat16* Vtb   = (__hip_bfloat16*)alloc((size_t)64 * TT * 64 * 2);
  __hip_bfloat16* Yb    = (__hip_bfloat16*)alloc((size_t)MTOT * 1024 * 2);

  k_cvt<<<(MTOT * 1024 / 8 + 255) / 256, 256, 0, stream>>>(x, xb, MTOT * 1024 / 8);
  k_transpose_cvt<<<dim3(3072 / 32, 1024 / 32), 256, 0, stream>>>(Wqkv, wqkvT, 1024, 3072);
  k_transpose_cvt<<<dim3(1024 / 32, 1024 / 32), 256, 0, stream>>>(Wproj, wpT, 1024, 1024);
  k_gemm2<<<dim3(32, 24), 512, 0, stream>>>(xb, wqkvT, bqkv, Qb, Kb, Vtb);
  k_flash<<<16 * 64, 256, 0, stream>>>(Qb, Kb, Vtb, Yb);
  k_gemm<<<dim3(64, 8), 256, 0, stream>>>(Yb, wpT, bproj, (float*)d_out);
}

// Round 7
// 166.320 us; speedup vs baseline: 1.1720x; 1.0101x over previous
//
#include <hip/hip_runtime.h>
#include <hip/hip_bf16.h>
#include <cstdint>
#include <math.h>

// Problem constants
#define DM   1024
#define NH   16
#define DH   64
#define BB   4
#define TT   2048
#define MTOT (BB*TT)   // 8192 rows

using short8 = __attribute__((ext_vector_type(8))) short;  // 8 bf16 (4 VGPRs)
using f32x4  = __attribute__((ext_vector_type(4))) float;

__device__ __forceinline__ f32x4 mfma16(short8 a, short8 b, f32x4 c) {
  return __builtin_amdgcn_mfma_f32_16x16x32_bf16(a, b, c, 0, 0, 0);
}

typedef const __attribute__((address_space(1))) unsigned int* as1_u32p;
typedef __attribute__((address_space(3))) unsigned int*       as3_u32p;

// async global->LDS, 16B per lane; LDS dest = wave-uniform base + lane*16 (linear)
__device__ __forceinline__ void gl_lds16(const void* g, void* l) {
  __builtin_amdgcn_global_load_lds(
      (as1_u32p)(reinterpret_cast<uintptr_t>(g)),
      (as3_u32p)((unsigned int)(reinterpret_cast<uintptr_t>(l))),
      16, 0, 0);
}

// XOR swizzle for tiles with 64-elem (128B) rows: 8 slots of 8 bf16; slot ^= row&7
__device__ __forceinline__ int swz64(int row, int col) {
  return row*64 + ((((col >> 3) ^ (row & 7)) << 3) | (col & 7));
}

__device__ __forceinline__ unsigned pkbf(float a, float b) {
  __hip_bfloat162 h = __float22bfloat162_rn(make_float2(a, b)); // x=lo, y=hi
  return *reinterpret_cast<unsigned*>(&h);
}

// xor16 lane exchange on the VALU pipe (not DS): v_permlane16_swap_b32 on (x,x)
// gives a=[r0,r0,r2,r2], b=[r1,r1,r3,r3] (16-lane rows); select by row parity.
__device__ __forceinline__ unsigned xor16v(unsigned x, bool odd) {
  unsigned a = x, b = x;
  asm("v_permlane16_swap_b32 %0, %1" : "+v"(a), "+v"(b));
  return odd ? a : b;
}
// permlane32_swap(d,s): d'=[d0,d1,s0,s1], s'=[d2,d3,s2,s3] (rows); select by parity.
__device__ __forceinline__ unsigned swap32sel(unsigned d, unsigned s, bool odd) {
  asm("v_permlane32_swap_b32 %0, %1" : "+v"(d), "+v"(s));
  return odd ? s : d;
}

// inline-asm LDS reads (opaque to alias analysis: no compiler-inserted vmcnt drains)
__device__ __forceinline__ short8 ldsr_o0(unsigned a) {
  short8 r; asm volatile("ds_read_b128 %0, %1" : "=v"(r) : "v"(a)); return r;
}
__device__ __forceinline__ short8 ldsr_o1(unsigned a) {
  short8 r; asm volatile("ds_read_b128 %0, %1 offset:2048" : "=v"(r) : "v"(a)); return r;
}
__device__ __forceinline__ short8 ldsr_o2(unsigned a) {
  short8 r; asm volatile("ds_read_b128 %0, %1 offset:4096" : "=v"(r) : "v"(a)); return r;
}
__device__ __forceinline__ short8 ldsr_o3(unsigned a) {
  short8 r; asm volatile("ds_read_b128 %0, %1 offset:6144" : "=v"(r) : "v"(a)); return r;
}

#define LGKM0  do { asm volatile("s_waitcnt lgkmcnt(0)"); __builtin_amdgcn_sched_barrier(0); } while(0)
#define VMCNT6 do { __builtin_amdgcn_sched_barrier(0); asm volatile("s_waitcnt vmcnt(6)"); __builtin_amdgcn_sched_barrier(0); } while(0)
#define VMCNT0 do { __builtin_amdgcn_sched_barrier(0); asm volatile("s_waitcnt vmcnt(0)"); __builtin_amdgcn_sched_barrier(0); } while(0)
#define BARRIER do { __builtin_amdgcn_s_barrier(); __builtin_amdgcn_sched_barrier(0); } while(0)

// ---------------- fp32 -> bf16 copy convert ----------------
__global__ __launch_bounds__(256) void k_cvt(const float* __restrict__ in,
                                             __hip_bfloat16* __restrict__ out, int n8) {
  int i = blockIdx.x * 256 + threadIdx.x;
  if (i >= n8) return;
  const float* p = in + (size_t)i * 8;
  short8 o;
#pragma unroll
  for (int j = 0; j < 8; ++j) {
    __hip_bfloat16 h = __float2bfloat16(p[j]);
    o[j] = *reinterpret_cast<short*>(&h);
  }
  *reinterpret_cast<short8*>(out + (size_t)i * 8) = o;
}

// ---------------- W [K][N] fp32 -> Wt [N][K] bf16 (tiled transpose) ----------------
__global__ __launch_bounds__(256) void k_transpose_cvt(const float* __restrict__ W,
                                                       __hip_bfloat16* __restrict__ Wt,
                                                       int K, int N) {
  __shared__ float tbuf[32][33];
  const int n0 = blockIdx.x * 32, k0 = blockIdx.y * 32;
  const int tx = threadIdx.x & 31, ty = threadIdx.x >> 5;
#pragma unroll
  for (int i = 0; i < 4; ++i)
    tbuf[ty + i*8][tx] = W[(size_t)(k0 + ty + i*8) * N + n0 + tx];
  __syncthreads();
#pragma unroll
  for (int i = 0; i < 4; ++i)
    Wt[(size_t)(n0 + ty + i*8) * K + k0 + tx] = __float2bfloat16(tbuf[tx][ty + i*8]);
}

// ---------------- 256x128 triple-buffered deep-pipeline QKV GEMM ----------------
__global__ __launch_bounds__(512, 2) void k_gemm2(const __hip_bfloat16* __restrict__ A,
                                                  const __hip_bfloat16* __restrict__ Bt,
                                                  const float* __restrict__ bias,
                                                  __hip_bfloat16* __restrict__ Qb,
                                                  __hip_bfloat16* __restrict__ Kb,
                                                  __hip_bfloat16* __restrict__ Vtb) {
  __shared__ __hip_bfloat16 As[3][256 * 64];
  __shared__ __hip_bfloat16 Bs[3][128 * 64];
  const int tid = threadIdx.x;
  const int l = tid & 63, w = tid >> 6;
  const int lr = l & 15, lg = l >> 4;
  const int wm = w >> 1, wn = w & 1;
  const int m0 = blockIdx.x * 256, n0 = blockIdx.y * 128;

  const int srow = tid >> 3;
  const int scol = (((tid & 7) ^ (srow & 7)) << 3);
  const size_t aoffs = (size_t)(m0 + srow) * 1024 + scol;
  const size_t boffs = (size_t)(n0 + srow) * 1024 + scol;
  const int ldst = tid * 8;

  auto stage = [&](int t, int s) {
    const int k0 = t * 64;
    __hip_bfloat16* as_ = &As[s][0];
    __hip_bfloat16* bs_ = &Bs[s][0];
#pragma unroll
    for (int rd = 0; rd < 4; ++rd)
      gl_lds16(A + aoffs + (size_t)rd * 65536 + k0, as_ + rd * 4096 + ldst);
#pragma unroll
    for (int rd = 0; rd < 2; ++rd)
      gl_lds16(Bt + boffs + (size_t)rd * 65536 + k0, bs_ + rd * 4096 + ldst);
  };

  const unsigned asLds = (unsigned)(uintptr_t)&As[0][0];
  const unsigned bsLds = (unsigned)(uintptr_t)&Bs[0][0];
  const unsigned aBase = asLds + 2u * ((wm*64 + lr) * 64 + ((lg ^ (lr & 7)) << 3));
  const unsigned bBase = bsLds + 2u * ((wn*64 + lr) * 64 + ((lg ^ (lr & 7)) << 3));

  stage(0, 0);
  stage(1, 1);
  VMCNT6;
  BARRIER;

  f32x4 acc[4][4] = {};
  short8 a_[4][2], b_[2][2];

#pragma unroll
  for (int t = 0; t < 16; ++t) {
    const int s = t % 3;
    const unsigned aB0 = aBase + (unsigned)s * 32768u;
    const unsigned aB1 = aB0 ^ 64u;
    const unsigned bB0 = bBase + (unsigned)s * 16384u;
    const unsigned bB1 = bB0 ^ 64u;
    if (t + 2 < 16) stage(t + 2, (t + 2) % 3);
    a_[0][0] = ldsr_o0(aB0); a_[1][0] = ldsr_o1(aB0); a_[2][0] = ldsr_o2(aB0); a_[3][0] = ldsr_o3(aB0);
    a_[0][1] = ldsr_o0(aB1); a_[1][1] = ldsr_o1(aB1); a_[2][1] = ldsr_o2(aB1); a_[3][1] = ldsr_o3(aB1);
    b_[0][0] = ldsr_o0(bB0); b_[1][0] = ldsr_o1(bB0);
    b_[0][1] = ldsr_o0(bB1); b_[1][1] = ldsr_o1(bB1);
    LGKM0;
    __builtin_amdgcn_s_setprio(1);
#pragma unroll
    for (int m = 0; m < 4; ++m)
#pragma unroll
      for (int n = 0; n < 2; ++n)
#pragma unroll
        for (int ks = 0; ks < 2; ++ks)
          acc[m][n] = mfma16(a_[m][ks], b_[n][ks], acc[m][n]);
    __builtin_amdgcn_s_setprio(0);
    b_[0][0] = ldsr_o2(bB0); b_[1][0] = ldsr_o3(bB0);
    b_[0][1] = ldsr_o2(bB1); b_[1][1] = ldsr_o3(bB1);
    LGKM0;
    __builtin_amdgcn_s_setprio(1);
#pragma unroll
    for (int m = 0; m < 4; ++m)
#pragma unroll
      for (int n = 0; n < 2; ++n)
#pragma unroll
        for (int ks = 0; ks < 2; ++ks)
          acc[m][n + 2] = mfma16(a_[m][ks], b_[n][ks], acc[m][n + 2]);
    __builtin_amdgcn_s_setprio(0);
    if (t <= 13) { VMCNT6; }
    else if (t == 14) { VMCNT0; }
    BARRIER;
  }

  __syncthreads();
  __hip_bfloat16* reg = &As[0][0] + w * 4096;
  const int colbase = n0 + wn * 64;
  const int which = colbase >> 10;
  const int hh = (colbase >> 6) & 15;
  const float qs = 0.18033688011112042f;     // 0.125 * log2(e) folded into Q
#pragma unroll
  for (int n = 0; n < 4; ++n) {
    const int lc = n * 16 + lr;
    const float bv = bias[colbase + lc];
#pragma unroll
    for (int m = 0; m < 4; ++m) {
#pragma unroll
      for (int r = 0; r < 4; ++r) {
        const int lrow = m * 16 + lg * 4 + r;
        float v = acc[m][n][r] + bv;
        if (which == 0) v *= qs;
        const __hip_bfloat16 hv = __float2bfloat16(v);
        if (which == 2) reg[swz64(lc, lrow)] = hv;
        else            reg[swz64(lrow, lc)] = hv;
      }
    }
  }
  const int rowbase = m0 + wm * 64;
  const int b = rowbase >> 11;
  const size_t bh = (size_t)b * 16 + hh;
  const int g = l >> 2, i = l & 3;
  if (which < 2) {
    __hip_bfloat16* base = (which == 0) ? Qb : Kb;
#pragma unroll
    for (int j = 0; j < 4; ++j) {
      const int lrow = j * 16 + g;
      const int t = (rowbase & 2047) + lrow;
      __hip_bfloat16* dst = base + (bh * TT + t) * 64 + i * 16;
      short8 y0 = *reinterpret_cast<const short8*>(&reg[swz64(lrow, i * 16)]);
      short8 y1 = *reinterpret_cast<const short8*>(&reg[swz64(lrow, i * 16 + 8)]);
      *reinterpret_cast<short8*>(dst) = y0;
      *reinterpret_cast<short8*>(dst + 8) = y1;
    }
  } else {
#pragma unroll
    for (int j = 0; j < 4; ++j) {
      const int dd = j * 16 + g;
      const int t = (rowbase & 2047) + i * 16;
      __hip_bfloat16* dst = Vtb + (bh * 64 + dd) * TT + t;
      short8 y0 = *reinterpret_cast<const short8*>(&reg[swz64(dd, i * 16)]);
      short8 y1 = *reinterpret_cast<const short8*>(&reg[swz64(dd, i * 16 + 8)]);
      *reinterpret_cast<short8*>(dst) = y0;
      *reinterpret_cast<short8*>(dst + 8) = y1;
    }
  }
}

// ---------------- 128x128 bf16 GEMM (proj): A[M][1024] @ Bt[N][1024]^T + bias -> fp32 ----------------
__global__ __launch_bounds__(256) void k_gemm(const __hip_bfloat16* __restrict__ A,
                                              const __hip_bfloat16* __restrict__ Bt,
                                              const float* __restrict__ bias,
                                              float* __restrict__ outF) {
  __shared__ __hip_bfloat16 As[128 * 64];
  __shared__ __hip_bfloat16 Bs[128 * 64];
  const int tid = threadIdx.x;
  const int l = tid & 63, w = tid >> 6;
  const int lr = l & 15, lg = l >> 4;
  const int wr = w >> 1, wc = w & 1;
  const int m0 = blockIdx.x * 128, n0 = blockIdx.y * 128;
  f32x4 acc[4][4] = {};
  for (int k0 = 0; k0 < 1024; k0 += 64) {
#pragma unroll
    for (int it = 0; it < 4; ++it) {
      int e = it * 2048 + tid * 8;
      int row = e >> 6;
      int lcol = ((((e >> 3) & 7) ^ (row & 7)) << 3);
      gl_lds16(A + (size_t)(m0 + row) * 1024 + k0 + lcol, &As[e]);
    }
#pragma unroll
    for (int it = 0; it < 4; ++it) {
      int e = it * 2048 + tid * 8;
      int row = e >> 6;
      int lcol = ((((e >> 3) & 7) ^ (row & 7)) << 3);
      gl_lds16(Bt + (size_t)(n0 + row) * 1024 + k0 + lcol, &Bs[e]);
    }
    __syncthreads();
#pragma unroll
    for (int ks = 0; ks < 2; ++ks) {
      short8 af[4], bf[4];
#pragma unroll
      for (int m = 0; m < 4; ++m)
        af[m] = *reinterpret_cast<const short8*>(&As[swz64(wr*64 + m*16 + lr, ks*32 + lg*8)]);
#pragma unroll
      for (int n = 0; n < 4; ++n)
        bf[n] = *reinterpret_cast<const short8*>(&Bs[swz64(wc*64 + n*16 + lr, ks*32 + lg*8)]);
#pragma unroll
      for (int m = 0; m < 4; ++m)
#pragma unroll
        for (int n = 0; n < 4; ++n)
          acc[m][n] = mfma16(af[m], bf[n], acc[m][n]);
    }
    __syncthreads();
  }
#pragma unroll
  for (int n = 0; n < 4; ++n) {
    const int col = n0 + wc*64 + n*16 + lr;
    const float bv = bias[col];
#pragma unroll
    for (int m = 0; m < 4; ++m)
#pragma unroll
      for (int r = 0; r < 4; ++r) {
        const int row = m0 + wr*64 + m*16 + lg*4 + r;
        outF[(size_t)row * 1024 + col] = acc[m][n][r] + bv;
      }
  }
}

// ---------------- causal flash attention (merged paired q-tiles, fixed-max softmax) ----------------
// One kci loop serves BOTH tiles: K/V fragment reads shared; P redistribution on the
// VALU pipe via v_permlane16/32_swap (no ds_bpermute) -> DS pipe only carries 8 b128/chunk.
__device__ __forceinline__ void tile_step(f32x4 s0, f32x4 s1, int kbase, int kmaxw, int qm,
                                          bool odd, short8 v0, short8 v1, short8 v2, short8 v3,
                                          f32x4 (&acc)[4], float& lrun) {
  if (kbase + 31 > kmaxw - 15) {       // diagonal chunk: per-element causal mask
#pragma unroll
    for (int r = 0; r < 4; ++r) {
      if (kbase + r > qm)      s0[r] = -INFINITY;
      if (kbase + 16 + r > qm) s1[r] = -INFINITY;
    }
  }
  float p0 = __builtin_amdgcn_exp2f(s0[0]), p1 = __builtin_amdgcn_exp2f(s0[1]);
  float p2 = __builtin_amdgcn_exp2f(s0[2]), p3 = __builtin_amdgcn_exp2f(s0[3]);
  float p4 = __builtin_amdgcn_exp2f(s1[0]), p5 = __builtin_amdgcn_exp2f(s1[1]);
  float p6 = __builtin_amdgcn_exp2f(s1[2]), p7 = __builtin_amdgcn_exp2f(s1[3]);
  lrun += ((p0 + p1) + (p2 + p3)) + ((p4 + p5) + (p6 + p7));
  const unsigned u0 = pkbf(p0, p1);    // keys (4lg, 4lg+1)
  const unsigned u1 = pkbf(p2, p3);    // keys (4lg+2, 4lg+3)
  const unsigned u2 = pkbf(p4, p5);    // keys 16+(4lg, 4lg+1)
  const unsigned u3 = pkbf(p6, p7);
  // stage 1: partner (lg^1) words via permlane16_swap (VALU)
  const unsigned e0 = xor16v(u0, odd);
  const unsigned e1 = xor16v(u1, odd);
  const unsigned e2 = xor16v(u2, odd);
  const unsigned e3 = xor16v(u3, odd);
  // stage 2: build low/high quads valid at all lanes
  const unsigned ql0 = odd ? e0 : u0;
  const unsigned ql1 = odd ? e1 : u1;
  const unsigned ql2 = odd ? u0 : e0;
  const unsigned ql3 = odd ? u1 : e1;
  const unsigned qh0 = odd ? e2 : u2;
  const unsigned qh1 = odd ? e3 : u3;
  const unsigned qh2 = odd ? u2 : e2;
  const unsigned qh3 = odd ? u3 : e3;
  // stage 3: +/-32-lane move via permlane32_swap
  union { unsigned u[4]; short8 s; } pw;
  pw.u[0] = swap32sel(ql0, qh0, odd);
  pw.u[1] = swap32sel(ql1, qh1, odd);
  pw.u[2] = swap32sel(ql2, qh2, odd);
  pw.u[3] = swap32sel(ql3, qh3, odd);
  const short8 pf = pw.s;
  acc[0] = mfma16(v0, pf, acc[0]);
  acc[1] = mfma16(v1, pf, acc[1]);
  acc[2] = mfma16(v2, pf, acc[2]);
  acc[3] = mfma16(v3, pf, acc[3]);
}

__device__ __forceinline__ void store_tile(__hip_bfloat16* Ylds, f32x4 (&acc)[4],
                                           float lrun, int q0, int w, int l,
                                           int lr, int lg, int bh,
                                           __hip_bfloat16* __restrict__ Y) {
  lrun += __shfl_xor(lrun, 16);
  lrun += __shfl_xor(lrun, 32);
  const float inv = 1.f / lrun;
#pragma unroll
  for (int nb = 0; nb < 4; ++nb) {
#pragma unroll
    for (int r = 0; r < 4; ++r) {
      const int d = nb * 16 + lg * 4 + r;
      Ylds[swz64(lr, d)] = __float2bfloat16(acc[nb][r] * inv);
    }
  }
  const int rr = l >> 2, part = l & 3;
  const int trow = q0 + w * 16 + rr;
  const int b = bh >> 4, h = bh & 15;
  short8 y0 = *reinterpret_cast<const short8*>(&Ylds[swz64(rr, part * 16)]);
  short8 y1 = *reinterpret_cast<const short8*>(&Ylds[swz64(rr, part * 16 + 8)]);
  __hip_bfloat16* dst = Y + ((size_t)b * TT + trow) * 1024 + h * 64 + part * 16;
  *reinterpret_cast<short8*>(dst) = y0;
  *reinterpret_cast<short8*>(dst + 8) = y1;
}

__global__ __launch_bounds__(256, 4) void k_flash(const __hip_bfloat16* __restrict__ Qb,
                                                  const __hip_bfloat16* __restrict__ Kb,
                                                  const __hip_bfloat16* __restrict__ Vtb,
                                                  __hip_bfloat16* __restrict__ Y) {
  __shared__ __hip_bfloat16 Klds[128 * 64];
  __shared__ __hip_bfloat16 Vtlds[64 * 128];
  const int tid = threadIdx.x;
  const int l = tid & 63, w = tid >> 6;
  const int lr = l & 15, lg = l >> 4;
  const bool odd = (lg & 1);
  const int p  = blockIdx.x >> 6;       // pair index 0..15
  const int bh = blockIdx.x & 63;
  const int q0A = p * 64, q0B = (31 - p) * 64;
  const __hip_bfloat16* Qp = Qb + (size_t)bh * TT * 64;
  const __hip_bfloat16* Kp = Kb + (size_t)bh * TT * 64;
  const __hip_bfloat16* Vp = Vtb + (size_t)bh * 64 * TT;
  const int qrowA = q0A + w * 16 + lr;
  const int qrowB = q0B + w * 16 + lr;
  const short8 qfA0 = *reinterpret_cast<const short8*>(Qp + (size_t)qrowA * 64 + lg * 8);
  const short8 qfA1 = *reinterpret_cast<const short8*>(Qp + (size_t)qrowA * 64 + 32 + lg * 8);
  const short8 qfB0 = *reinterpret_cast<const short8*>(Qp + (size_t)qrowB * 64 + lg * 8);
  const short8 qfB1 = *reinterpret_cast<const short8*>(Qp + (size_t)qrowB * 64 + 32 + lg * 8);
  f32x4 accA[4] = {}, accB[4] = {};
  float lA = 0.f, lB = 0.f;

  const int ka  = lr * 64 + ((lg ^ (lr & 7)) << 3);
  const int va  = lr * 128 + ((lg ^ (lr & 15)) << 3);

  const __hip_bfloat16* gk[4];
  const __hip_bfloat16* gv[4];
  __hip_bfloat16* lk[4];
  __hip_bfloat16* lv[4];
#pragma unroll
  for (int it = 0; it < 4; ++it) {
    int e = it * 2048 + tid * 8;
    int rowk = e >> 6;
    int lcolk = ((((e >> 3) & 7) ^ (rowk & 7)) << 3);
    gk[it] = Kp + (size_t)rowk * 64 + lcolk;
    lk[it] = &Klds[e];
    int rowv = e >> 7;
    int lcolv = ((((e >> 3) & 15) ^ (rowv & 15)) << 3);
    gv[it] = Vp + (size_t)rowv * TT + lcolv;
    lv[it] = &Vtlds[e];
  }

  const int kmaxwA = q0A + w * 16 + 15;
  const int kmaxwB = q0B + w * 16 + 15;
  const int qmA = qrowA - lg * 4;
  const int qmB = qrowB - lg * 4;
  const int nblk = (q0B + 63) / 128 + 1;   // B's range covers A's
  for (int blk = 0; blk < nblk; ++blk) {
    const int kv0 = blk * 128;
#pragma unroll
    for (int it = 0; it < 4; ++it) {
      gl_lds16(gk[it], lk[it]);
      gk[it] += 128 * 64;
    }
#pragma unroll
    for (int it = 0; it < 4; ++it) {
      gl_lds16(gv[it], lv[it]);
      gv[it] += 128;
    }
    __syncthreads();
#pragma unroll
    for (int kci = 0; kci < 4; ++kci) {
      const int kbase = kv0 + kci * 32;
      if (kbase > kmaxwB) break;       // wave-uniform (B bounds the pair)
      // shared K fragments
      const int kb = ka + kci * 2048;
      const short8 kf00 = *reinterpret_cast<const short8*>(&Klds[kb]);
      const short8 kf10 = *reinterpret_cast<const short8*>(&Klds[kb + 1024]);
      const short8 kf01 = *reinterpret_cast<const short8*>(&Klds[kb ^ 32]);
      const short8 kf11 = *reinterpret_cast<const short8*>(&Klds[(kb + 1024) ^ 32]);
      f32x4 sB0 = {}, sB1 = {};
      sB0 = mfma16(kf00, qfB0, sB0);
      sB1 = mfma16(kf10, qfB0, sB1);
      sB0 = mfma16(kf01, qfB1, sB0);
      sB1 = mfma16(kf11, qfB1, sB1);
      const bool aAct = (kbase <= kmaxwA);
      f32x4 sA0 = {}, sA1 = {};
      if (aAct) {
        sA0 = mfma16(kf00, qfA0, sA0);
        sA1 = mfma16(kf10, qfA0, sA1);
        sA0 = mfma16(kf01, qfA1, sA0);
        sA1 = mfma16(kf11, qfA1, sA1);
      }
      // shared V fragments
      const int vb = va ^ (kci * 32);
      const short8 v0 = *reinterpret_cast<const short8*>(&Vtlds[vb]);
      const short8 v1 = *reinterpret_cast<const short8*>(&Vtlds[vb + 2048]);
      const short8 v2 = *reinterpret_cast<const short8*>(&Vtlds[vb + 4096]);
      const short8 v3 = *reinterpret_cast<const short8*>(&Vtlds[vb + 6144]);
      tile_step(sB0, sB1, kbase, kmaxwB, qmB, odd, v0, v1, v2, v3, accB, lB);
      if (aAct)
        tile_step(sA0, sA1, kbase, kmaxwA, qmA, odd, v0, v1, v2, v3, accA, lA);
    }
    __syncthreads();
  }
  __hip_bfloat16* Ylds = Klds + w * 1024;
  store_tile(Ylds, accA, lA, q0A, w, l, lr, lg, bh, Y);
  store_tile(Ylds, accB, lB, q0B, w, l, lr, lg, bh, Y);
}

// ---------------- launch ----------------
extern "C" void kernel_launch(void* const* d_in, const int* in_sizes, int n_in,
                              void* d_out, int out_size, void* d_ws, size_t ws_size,
                              hipStream_t stream) {
  const float* x     = (const float*)d_in[0];
  const float* Wqkv  = (const float*)d_in[1];
  const float* bqkv  = (const float*)d_in[2];
  const float* Wproj = (const float*)d_in[3];
  const float* bproj = (const float*)d_in[4];

  char* ws = (char*)d_ws;
  size_t off = 0;
  auto alloc = [&](size_t bytes) {
    char* p = ws + off;
    off += (bytes + 255) & ~(size_t)255;
    return p;
  };
  __hip_bfloat16* xb    = (__hip_bfloat16*)alloc((size_t)MTOT * 1024 * 2);
  __hip_bfloat16* wqkvT = (__hip_bfloat16*)alloc((size_t)3072 * 1024 * 2);
  __hip_bfloat16* wpT   = (__hip_bfloat16*)alloc((size_t)1024 * 1024 * 2);
  __hip_bfloat16* Qb    = (__hip_bfloat16*)alloc((size_t)64 * TT * 64 * 2);
  __hip_bfloat16* Kb    = (__hip_bfloat16*)alloc((size_t)64 * TT * 64 * 2);
  __hip_bfloat16* Vtb   = (__hip_bfloat16*)alloc((size_t)64 * TT * 64 * 2);
  __hip_bfloat16* Yb    = (__hip_bfloat16*)alloc((size_t)MTOT * 1024 * 2);

  k_cvt<<<(MTOT * 1024 / 8 + 255) / 256, 256, 0, stream>>>(x, xb, MTOT * 1024 / 8);
  k_transpose_cvt<<<dim3(3072 / 32, 1024 / 32), 256, 0, stream>>>(Wqkv, wqkvT, 1024, 3072);
  k_transpose_cvt<<<dim3(1024 / 32, 1024 / 32), 256, 0, stream>>>(Wproj, wpT, 1024, 1024);
  k_gemm2<<<dim3(32, 24), 512, 0, stream>>>(xb, wqkvT, bqkv, Qb, Kb, Vtb);
  k_flash<<<16 * 64, 256, 0, stream>>>(Qb, Kb, Vtb, Yb);
  k_gemm<<<dim3(64, 8), 256, 0, stream>>>(Yb, wpT, bproj, (float*)d_out);
}

// Round 8
// 152.311 us; speedup vs baseline: 1.2798x; 1.0920x over previous
//
#include <hip/hip_runtime.h>
#include <hip/hip_bf16.h>
#include <cstdint>
#include <math.h>

// Problem constants
#define DM   1024
#define NH   16
#define DH   64
#define BB   4
#define TT   2048
#define MTOT (BB*TT)   // 8192 rows

using short8 = __attribute__((ext_vector_type(8))) short;  // 8 bf16 (4 VGPRs)
using f32x4  = __attribute__((ext_vector_type(4))) float;

__device__ __forceinline__ f32x4 mfma16(short8 a, short8 b, f32x4 c) {
  return __builtin_amdgcn_mfma_f32_16x16x32_bf16(a, b, c, 0, 0, 0);
}

typedef const __attribute__((address_space(1))) unsigned int* as1_u32p;
typedef __attribute__((address_space(3))) unsigned int*       as3_u32p;

// async global->LDS, 16B per lane; LDS dest = wave-uniform base + lane*16 (linear)
__device__ __forceinline__ void gl_lds16(const void* g, void* l) {
  __builtin_amdgcn_global_load_lds(
      (as1_u32p)(reinterpret_cast<uintptr_t>(g)),
      (as3_u32p)((unsigned int)(reinterpret_cast<uintptr_t>(l))),
      16, 0, 0);
}

// XOR swizzle for tiles with 64-elem (128B) rows: 8 slots of 8 bf16; slot ^= row&7
__device__ __forceinline__ int swz64(int row, int col) {
  return row*64 + ((((col >> 3) ^ (row & 7)) << 3) | (col & 7));
}

__device__ __forceinline__ unsigned pkbf(float a, float b) {
  __hip_bfloat162 h = __float22bfloat162_rn(make_float2(a, b)); // x=lo, y=hi
  return *reinterpret_cast<unsigned*>(&h);
}

// permlane swaps (VALU pipe). Verified row semantics (involutions):
// perm16(d,s): d'=[d0,s0,d2,s2], s'=[d1,s1,d3,s3]   (16-lane rows)
// perm32(d,s): d'=[d0,d1,s0,s1], s'=[d2,d3,s2,s3]
__device__ __forceinline__ void perm16p(unsigned &a, unsigned &b) {
  asm("v_permlane16_swap_b32 %0, %1" : "+v"(a), "+v"(b));
}
__device__ __forceinline__ void perm32p(unsigned &a, unsigned &b) {
  asm("v_permlane32_swap_b32 %0, %1" : "+v"(a), "+v"(b));
}

// inline-asm LDS reads (opaque to alias analysis: no compiler-inserted vmcnt drains)
__device__ __forceinline__ short8 ldsr_o0(unsigned a) {
  short8 r; asm volatile("ds_read_b128 %0, %1" : "=v"(r) : "v"(a)); return r;
}
__device__ __forceinline__ short8 ldsr_o1(unsigned a) {
  short8 r; asm volatile("ds_read_b128 %0, %1 offset:2048" : "=v"(r) : "v"(a)); return r;
}
__device__ __forceinline__ short8 ldsr_o2(unsigned a) {
  short8 r; asm volatile("ds_read_b128 %0, %1 offset:4096" : "=v"(r) : "v"(a)); return r;
}
__device__ __forceinline__ short8 ldsr_o3(unsigned a) {
  short8 r; asm volatile("ds_read_b128 %0, %1 offset:6144" : "=v"(r) : "v"(a)); return r;
}

#define LGKM0  do { asm volatile("s_waitcnt lgkmcnt(0)"); __builtin_amdgcn_sched_barrier(0); } while(0)
#define VMCNT6 do { __builtin_amdgcn_sched_barrier(0); asm volatile("s_waitcnt vmcnt(6)"); __builtin_amdgcn_sched_barrier(0); } while(0)
#define VMCNT0 do { __builtin_amdgcn_sched_barrier(0); asm volatile("s_waitcnt vmcnt(0)"); __builtin_amdgcn_sched_barrier(0); } while(0)
#define BARRIER do { __builtin_amdgcn_s_barrier(); __builtin_amdgcn_sched_barrier(0); } while(0)

// ---------------- fp32 -> bf16 copy convert ----------------
__global__ __launch_bounds__(256) void k_cvt(const float* __restrict__ in,
                                             __hip_bfloat16* __restrict__ out, int n8) {
  int i = blockIdx.x * 256 + threadIdx.x;
  if (i >= n8) return;
  const float* p = in + (size_t)i * 8;
  short8 o;
#pragma unroll
  for (int j = 0; j < 8; ++j) {
    __hip_bfloat16 h = __float2bfloat16(p[j]);
    o[j] = *reinterpret_cast<short*>(&h);
  }
  *reinterpret_cast<short8*>(out + (size_t)i * 8) = o;
}

// ---------------- W [K][N] fp32 -> Wt [N][K] bf16 (tiled transpose) ----------------
__global__ __launch_bounds__(256) void k_transpose_cvt(const float* __restrict__ W,
                                                       __hip_bfloat16* __restrict__ Wt,
                                                       int K, int N) {
  __shared__ float tbuf[32][33];
  const int n0 = blockIdx.x * 32, k0 = blockIdx.y * 32;
  const int tx = threadIdx.x & 31, ty = threadIdx.x >> 5;
#pragma unroll
  for (int i = 0; i < 4; ++i)
    tbuf[ty + i*8][tx] = W[(size_t)(k0 + ty + i*8) * N + n0 + tx];
  __syncthreads();
#pragma unroll
  for (int i = 0; i < 4; ++i)
    Wt[(size_t)(n0 + ty + i*8) * K + k0 + tx] = __float2bfloat16(tbuf[tx][ty + i*8]);
}

// ---------------- 256x128 triple-buffered deep-pipeline GEMM ----------------
// EPI=0: QKV epilogue (LDS-bounce scatter to Q/K/Vt). EPI=1: fp32 out + bias.
template <int EPI>
__global__ __launch_bounds__(512, 2) void k_gemm2(const __hip_bfloat16* __restrict__ A,
                                                  const __hip_bfloat16* __restrict__ Bt,
                                                  const float* __restrict__ bias,
                                                  float* __restrict__ outF,
                                                  __hip_bfloat16* __restrict__ Qb,
                                                  __hip_bfloat16* __restrict__ Kb,
                                                  __hip_bfloat16* __restrict__ Vtb) {
  __shared__ __hip_bfloat16 As[3][256 * 64];
  __shared__ __hip_bfloat16 Bs[3][128 * 64];
  const int tid = threadIdx.x;
  const int l = tid & 63, w = tid >> 6;
  const int lr = l & 15, lg = l >> 4;
  const int wm = w >> 1, wn = w & 1;
  const int m0 = blockIdx.x * 256, n0 = blockIdx.y * 128;

  const int srow = tid >> 3;
  const int scol = (((tid & 7) ^ (srow & 7)) << 3);
  const size_t aoffs = (size_t)(m0 + srow) * 1024 + scol;
  const size_t boffs = (size_t)(n0 + srow) * 1024 + scol;
  const int ldst = tid * 8;

  auto stage = [&](int t, int s) {
    const int k0 = t * 64;
    __hip_bfloat16* as_ = &As[s][0];
    __hip_bfloat16* bs_ = &Bs[s][0];
#pragma unroll
    for (int rd = 0; rd < 4; ++rd)
      gl_lds16(A + aoffs + (size_t)rd * 65536 + k0, as_ + rd * 4096 + ldst);
#pragma unroll
    for (int rd = 0; rd < 2; ++rd)
      gl_lds16(Bt + boffs + (size_t)rd * 65536 + k0, bs_ + rd * 4096 + ldst);
  };

  const unsigned asLds = (unsigned)(uintptr_t)&As[0][0];
  const unsigned bsLds = (unsigned)(uintptr_t)&Bs[0][0];
  const unsigned aBase = asLds + 2u * ((wm*64 + lr) * 64 + ((lg ^ (lr & 7)) << 3));
  const unsigned bBase = bsLds + 2u * ((wn*64 + lr) * 64 + ((lg ^ (lr & 7)) << 3));

  stage(0, 0);
  stage(1, 1);
  VMCNT6;
  BARRIER;

  f32x4 acc[4][4] = {};
  short8 a_[4][2], b_[2][2];

#pragma unroll
  for (int t = 0; t < 16; ++t) {
    const int s = t % 3;
    const unsigned aB0 = aBase + (unsigned)s * 32768u;
    const unsigned aB1 = aB0 ^ 64u;
    const unsigned bB0 = bBase + (unsigned)s * 16384u;
    const unsigned bB1 = bB0 ^ 64u;
    if (t + 2 < 16) stage(t + 2, (t + 2) % 3);
    a_[0][0] = ldsr_o0(aB0); a_[1][0] = ldsr_o1(aB0); a_[2][0] = ldsr_o2(aB0); a_[3][0] = ldsr_o3(aB0);
    a_[0][1] = ldsr_o0(aB1); a_[1][1] = ldsr_o1(aB1); a_[2][1] = ldsr_o2(aB1); a_[3][1] = ldsr_o3(aB1);
    b_[0][0] = ldsr_o0(bB0); b_[1][0] = ldsr_o1(bB0);
    b_[0][1] = ldsr_o0(bB1); b_[1][1] = ldsr_o1(bB1);
    LGKM0;
    __builtin_amdgcn_s_setprio(1);
#pragma unroll
    for (int m = 0; m < 4; ++m)
#pragma unroll
      for (int n = 0; n < 2; ++n)
#pragma unroll
        for (int ks = 0; ks < 2; ++ks)
          acc[m][n] = mfma16(a_[m][ks], b_[n][ks], acc[m][n]);
    __builtin_amdgcn_s_setprio(0);
    b_[0][0] = ldsr_o2(bB0); b_[1][0] = ldsr_o3(bB0);
    b_[0][1] = ldsr_o2(bB1); b_[1][1] = ldsr_o3(bB1);
    LGKM0;
    __builtin_amdgcn_s_setprio(1);
#pragma unroll
    for (int m = 0; m < 4; ++m)
#pragma unroll
      for (int n = 0; n < 2; ++n)
#pragma unroll
        for (int ks = 0; ks < 2; ++ks)
          acc[m][n + 2] = mfma16(a_[m][ks], b_[n][ks], acc[m][n + 2]);
    __builtin_amdgcn_s_setprio(0);
    if (t <= 13) { VMCNT6; }
    else if (t == 14) { VMCNT0; }
    BARRIER;
  }

  __syncthreads();
  if (EPI == 0) {
    __hip_bfloat16* reg = &As[0][0] + w * 4096;
    const int colbase = n0 + wn * 64;
    const int which = colbase >> 10;
    const int hh = (colbase >> 6) & 15;
    const float qs = 0.18033688011112042f;     // 0.125 * log2(e) folded into Q
#pragma unroll
    for (int n = 0; n < 4; ++n) {
      const int lc = n * 16 + lr;
      const float bv = bias[colbase + lc];
#pragma unroll
      for (int m = 0; m < 4; ++m) {
#pragma unroll
        for (int r = 0; r < 4; ++r) {
          const int lrow = m * 16 + lg * 4 + r;
          float v = acc[m][n][r] + bv;
          if (which == 0) v *= qs;
          const __hip_bfloat16 hv = __float2bfloat16(v);
          if (which == 2) reg[swz64(lc, lrow)] = hv;
          else            reg[swz64(lrow, lc)] = hv;
        }
      }
    }
    const int rowbase = m0 + wm * 64;
    const int b = rowbase >> 11;
    const size_t bh = (size_t)b * 16 + hh;
    const int g = l >> 2, i = l & 3;
    if (which < 2) {
      __hip_bfloat16* base = (which == 0) ? Qb : Kb;
#pragma unroll
      for (int j = 0; j < 4; ++j) {
        const int lrow = j * 16 + g;
        const int t = (rowbase & 2047) + lrow;
        __hip_bfloat16* dst = base + (bh * TT + t) * 64 + i * 16;
        short8 y0 = *reinterpret_cast<const short8*>(&reg[swz64(lrow, i * 16)]);
        short8 y1 = *reinterpret_cast<const short8*>(&reg[swz64(lrow, i * 16 + 8)]);
        *reinterpret_cast<short8*>(dst) = y0;
        *reinterpret_cast<short8*>(dst + 8) = y1;
      }
    } else {
#pragma unroll
      for (int j = 0; j < 4; ++j) {
        const int dd = j * 16 + g;
        const int t = (rowbase & 2047) + i * 16;
        __hip_bfloat16* dst = Vtb + (bh * 64 + dd) * TT + t;
        short8 y0 = *reinterpret_cast<const short8*>(&reg[swz64(dd, i * 16)]);
        short8 y1 = *reinterpret_cast<const short8*>(&reg[swz64(dd, i * 16 + 8)]);
        *reinterpret_cast<short8*>(dst) = y0;
        *reinterpret_cast<short8*>(dst + 8) = y1;
      }
    }
  } else {
#pragma unroll
    for (int n = 0; n < 4; ++n) {
      const int col = n0 + wn * 64 + n * 16 + lr;
      const float bv = bias[col];
#pragma unroll
      for (int m = 0; m < 4; ++m)
#pragma unroll
        for (int r = 0; r < 4; ++r) {
          const int row = m0 + wm * 64 + m * 16 + lg * 4 + r;
          outF[(size_t)row * 1024 + col] = acc[m][n][r] + bv;
        }
    }
  }
}

// ---------------- causal flash attention ----------------
// Merged paired q-tiles, fixed-max softmax, sigma-permuted K rows so the P->PV
// redistribution is exactly 2x permlane16_swap + 2x permlane32_swap (no cndmask).
// sigma swaps key pairs {2,3}<->{8,9}, {6,7}<->{12,13} per 16 (r^10 when bit1!=bit3);
// lane lg's scores then cover keys base_lg + {0,1,8,9} (+16 for s1),
// base_lg = ((lg&1)<<2)|(lg&2).
__device__ __forceinline__ void tile_step(f32x4 s0, f32x4 s1, int kbase, int kmaxw, int qmb,
                                          short8 v0, short8 v1, short8 v2, short8 v3,
                                          f32x4 (&acc)[4], float& lrun) {
  if (kbase + 31 > kmaxw - 15) {       // diagonal chunk: per-element causal mask
#pragma unroll
    for (int r = 0; r < 4; ++r) {
      const int off = (r & 1) + ((r & 2) << 2);   // 0,1,8,9
      if (kbase + off > qmb)      s0[r] = -INFINITY;
      if (kbase + 16 + off > qmb) s1[r] = -INFINITY;
    }
  }
  float p0 = __builtin_amdgcn_exp2f(s0[0]), p1 = __builtin_amdgcn_exp2f(s0[1]);
  float p2 = __builtin_amdgcn_exp2f(s0[2]), p3 = __builtin_amdgcn_exp2f(s0[3]);
  float p4 = __builtin_amdgcn_exp2f(s1[0]), p5 = __builtin_amdgcn_exp2f(s1[1]);
  float p6 = __builtin_amdgcn_exp2f(s1[2]), p7 = __builtin_amdgcn_exp2f(s1[3]);
  lrun += ((p0 + p1) + (p2 + p3)) + ((p4 + p5) + (p6 + p7));
  unsigned u0 = pkbf(p0, p1);
  unsigned u1 = pkbf(p2, p3);
  unsigned u2 = pkbf(p4, p5);
  unsigned u3 = pkbf(p6, p7);
  // native permlane redistribution (4 instructions, all outputs used)
  perm16p(u0, u1);   // u0=[lg0.u0,lg0.u1,lg2.u0,lg2.u1], u1=[lg1...,lg3...]
  perm16p(u2, u3);
  perm32p(u0, u2);   // u0=w0, u2=w1
  perm32p(u1, u3);   // u1=w2, u3=w3
  union { unsigned u[4]; short8 s; } pw;
  pw.u[0] = u0; pw.u[1] = u2; pw.u[2] = u1; pw.u[3] = u3;
  const short8 pf = pw.s;
  acc[0] = mfma16(v0, pf, acc[0]);
  acc[1] = mfma16(v1, pf, acc[1]);
  acc[2] = mfma16(v2, pf, acc[2]);
  acc[3] = mfma16(v3, pf, acc[3]);
}

__device__ __forceinline__ void store_tile(__hip_bfloat16* Ylds, f32x4 (&acc)[4],
                                           float lrun, int q0, int w, int l,
                                           int lr, int lg, int bh,
                                           __hip_bfloat16* __restrict__ Y) {
  lrun += __shfl_xor(lrun, 16);
  lrun += __shfl_xor(lrun, 32);
  const float inv = 1.f / lrun;
#pragma unroll
  for (int nb = 0; nb < 4; ++nb) {
#pragma unroll
    for (int r = 0; r < 4; ++r) {
      const int d = nb * 16 + lg * 4 + r;
      Ylds[swz64(lr, d)] = __float2bfloat16(acc[nb][r] * inv);
    }
  }
  const int rr = l >> 2, part = l & 3;
  const int trow = q0 + w * 16 + rr;
  const int b = bh >> 4, h = bh & 15;
  short8 y0 = *reinterpret_cast<const short8*>(&Ylds[swz64(rr, part * 16)]);
  short8 y1 = *reinterpret_cast<const short8*>(&Ylds[swz64(rr, part * 16 + 8)]);
  __hip_bfloat16* dst = Y + ((size_t)b * TT + trow) * 1024 + h * 64 + part * 16;
  *reinterpret_cast<short8*>(dst) = y0;
  *reinterpret_cast<short8*>(dst + 8) = y1;
}

__global__ __launch_bounds__(256, 4) void k_flash(const __hip_bfloat16* __restrict__ Qb,
                                                  const __hip_bfloat16* __restrict__ Kb,
                                                  const __hip_bfloat16* __restrict__ Vtb,
                                                  __hip_bfloat16* __restrict__ Y) {
  __shared__ __hip_bfloat16 Klds[128 * 64];
  __shared__ __hip_bfloat16 Vtlds[64 * 128];
  const int tid = threadIdx.x;
  const int l = tid & 63, w = tid >> 6;
  const int lr = l & 15, lg = l >> 4;
  const int p  = blockIdx.x >> 6;       // pair index 0..15
  const int bh = blockIdx.x & 63;
  const int q0A = p * 64, q0B = (31 - p) * 64;
  const __hip_bfloat16* Qp = Qb + (size_t)bh * TT * 64;
  const __hip_bfloat16* Kp = Kb + (size_t)bh * TT * 64;
  const __hip_bfloat16* Vp = Vtb + (size_t)bh * 64 * TT;
  const int qrowA = q0A + w * 16 + lr;
  const int qrowB = q0B + w * 16 + lr;
  const short8 qfA0 = *reinterpret_cast<const short8*>(Qp + (size_t)qrowA * 64 + lg * 8);
  const short8 qfA1 = *reinterpret_cast<const short8*>(Qp + (size_t)qrowA * 64 + 32 + lg * 8);
  const short8 qfB0 = *reinterpret_cast<const short8*>(Qp + (size_t)qrowB * 64 + lg * 8);
  const short8 qfB1 = *reinterpret_cast<const short8*>(Qp + (size_t)qrowB * 64 + 32 + lg * 8);
  f32x4 accA[4] = {}, accB[4] = {};
  float lA = 0.f, lB = 0.f;

  const int ka  = lr * 64 + ((lg ^ (lr & 7)) << 3);
  const int va  = lr * 128 + ((lg ^ (lr & 15)) << 3);

  const __hip_bfloat16* gk[4];
  const __hip_bfloat16* gv[4];
  __hip_bfloat16* lk[4];
  __hip_bfloat16* lv[4];
#pragma unroll
  for (int it = 0; it < 4; ++it) {
    int e = it * 2048 + tid * 8;
    int rowk = e >> 6;                 // LDS dest row (position)
    int lcolk = ((((e >> 3) & 7) ^ (rowk & 7)) << 3);
    // sigma source-row remap: position rowk holds global key sigma(rowk)
    int rk = rowk & 15;
    int srk = (((rk >> 1) ^ (rk >> 3)) & 1) ? (rk ^ 10) : rk;
    int rowks = (rowk & ~15) | srk;
    gk[it] = Kp + (size_t)rowks * 64 + lcolk;
    lk[it] = &Klds[e];
    int rowv = e >> 7;
    int lcolv = ((((e >> 3) & 15) ^ (rowv & 15)) << 3);
    gv[it] = Vp + (size_t)rowv * TT + lcolv;
    lv[it] = &Vtlds[e];
  }

  const int kmaxwA = q0A + w * 16 + 15;
  const int kmaxwB = q0B + w * 16 + 15;
  const int base_lg = ((lg & 1) << 2) | (lg & 2);
  const int qmbA = qrowA - base_lg;
  const int qmbB = qrowB - base_lg;
  const int nblk = (q0B + 63) / 128 + 1;   // B's range covers A's
  for (int blk = 0; blk < nblk; ++blk) {
    const int kv0 = blk * 128;
#pragma unroll
    for (int it = 0; it < 4; ++it) {
      gl_lds16(gk[it], lk[it]);
      gk[it] += 128 * 64;
    }
#pragma unroll
    for (int it = 0; it < 4; ++it) {
      gl_lds16(gv[it], lv[it]);
      gv[it] += 128;
    }
    __syncthreads();
#pragma unroll
    for (int kci = 0; kci < 4; ++kci) {
      const int kbase = kv0 + kci * 32;
      if (kbase > kmaxwB) break;       // wave-uniform (B bounds the pair)
      // shared K fragments
      const int kb = ka + kci * 2048;
      const short8 kf00 = *reinterpret_cast<const short8*>(&Klds[kb]);
      const short8 kf10 = *reinterpret_cast<const short8*>(&Klds[kb + 1024]);
      const short8 kf01 = *reinterpret_cast<const short8*>(&Klds[kb ^ 32]);
      const short8 kf11 = *reinterpret_cast<const short8*>(&Klds[(kb + 1024) ^ 32]);
      f32x4 sB0 = {}, sB1 = {};
      sB0 = mfma16(kf00, qfB0, sB0);
      sB1 = mfma16(kf10, qfB0, sB1);
      sB0 = mfma16(kf01, qfB1, sB0);
      sB1 = mfma16(kf11, qfB1, sB1);
      const bool aAct = (kbase <= kmaxwA);
      f32x4 sA0 = {}, sA1 = {};
      if (aAct) {
        sA0 = mfma16(kf00, qfA0, sA0);
        sA1 = mfma16(kf10, qfA0, sA1);
        sA0 = mfma16(kf01, qfA1, sA0);
        sA1 = mfma16(kf11, qfA1, sA1);
      }
      // shared V fragments
      const int vb = va ^ (kci * 32);
      const short8 v0 = *reinterpret_cast<const short8*>(&Vtlds[vb]);
      const short8 v1 = *reinterpret_cast<const short8*>(&Vtlds[vb + 2048]);
      const short8 v2 = *reinterpret_cast<const short8*>(&Vtlds[vb + 4096]);
      const short8 v3 = *reinterpret_cast<const short8*>(&Vtlds[vb + 6144]);
      tile_step(sB0, sB1, kbase, kmaxwB, qmbB, v0, v1, v2, v3, accB, lB);
      if (aAct)
        tile_step(sA0, sA1, kbase, kmaxwA, qmbA, v0, v1, v2, v3, accA, lA);
    }
    __syncthreads();
  }
  __hip_bfloat16* Ylds = Klds + w * 1024;
  store_tile(Ylds, accA, lA, q0A, w, l, lr, lg, bh, Y);
  store_tile(Ylds, accB, lB, q0B, w, l, lr, lg, bh, Y);
}

// ---------------- launch ----------------
extern "C" void kernel_launch(void* const* d_in, const int* in_sizes, int n_in,
                              void* d_out, int out_size, void* d_ws, size_t ws_size,
                              hipStream_t stream) {
  const float* x     = (const float*)d_in[0];
  const float* Wqkv  = (const float*)d_in[1];
  const float* bqkv  = (const float*)d_in[2];
  const float* Wproj = (const float*)d_in[3];
  const float* bproj = (const float*)d_in[4];

  char* ws = (char*)d_ws;
  size_t off = 0;
  auto alloc = [&](size_t bytes) {
    char* p = ws + off;
    off += (bytes + 255) & ~(size_t)255;
    return p;
  };
  __hip_bfloat16* xb    = (__hip_bfloat16*)alloc((size_t)MTOT * 1024 * 2);
  __hip_bfloat16* wqkvT = (__hip_bfloat16*)alloc((size_t)3072 * 1024 * 2);
  __hip_bfloat16* wpT   = (__hip_bfloat16*)alloc((size_t)1024 * 1024 * 2);
  __hip_bfloat16* Qb    = (__hip_bfloat16*)alloc((size_t)64 * TT * 64 * 2);
  __hip_bfloat16* Kb    = (__hip_bfloat16*)alloc((size_t)64 * TT * 64 * 2);
  __hip_bfloat16* Vtb   = (__hip_bfloat16*)alloc((size_t)64 * TT * 64 * 2);
  __hip_bfloat16* Yb    = (__hip_bfloat16*)alloc((size_t)MTOT * 1024 * 2);

  k_cvt<<<(MTOT * 1024 / 8 + 255) / 256, 256, 0, stream>>>(x, xb, MTOT * 1024 / 8);
  k_transpose_cvt<<<dim3(3072 / 32, 1024 / 32), 256, 0, stream>>>(Wqkv, wqkvT, 1024, 3072);
  k_transpose_cvt<<<dim3(1024 / 32, 1024 / 32), 256, 0, stream>>>(Wproj, wpT, 1024, 1024);
  k_gemm2<0><<<dim3(32, 24), 512, 0, stream>>>(xb, wqkvT, bqkv, nullptr, Qb, Kb, Vtb);
  k_flash<<<16 * 64, 256, 0, stream>>>(Qb, Kb, Vtb, Yb);
  k_gemm2<1><<<dim3(32, 8), 512, 0, stream>>>(Yb, wpT, bproj, (float*)d_out,
                                              nullptr, nullptr, nullptr);
}

// Round 9
// 147.114 us; speedup vs baseline: 1.3251x; 1.0353x over previous
//
#include <hip/hip_runtime.h>
#include <hip/hip_bf16.h>
#include <cstdint>
#include <math.h>

// Problem constants
#define DM   1024
#define NH   16
#define DH   64
#define BB   4
#define TT   2048
#define MTOT (BB*TT)   // 8192 rows

using short8 = __attribute__((ext_vector_type(8))) short;  // 8 bf16 (4 VGPRs)
using f32x4  = __attribute__((ext_vector_type(4))) float;

__device__ __forceinline__ f32x4 mfma16(short8 a, short8 b, f32x4 c) {
  return __builtin_amdgcn_mfma_f32_16x16x32_bf16(a, b, c, 0, 0, 0);
}

typedef const __attribute__((address_space(1))) unsigned int* as1_u32p;
typedef __attribute__((address_space(3))) unsigned int*       as3_u32p;

// async global->LDS, 16B per lane; LDS dest = wave-uniform base + lane*16 (linear)
__device__ __forceinline__ void gl_lds16(const void* g, void* l) {
  __builtin_amdgcn_global_load_lds(
      (as1_u32p)(reinterpret_cast<uintptr_t>(g)),
      (as3_u32p)((unsigned int)(reinterpret_cast<uintptr_t>(l))),
      16, 0, 0);
}

// XOR swizzle for tiles with 64-elem (128B) rows: 8 slots of 8 bf16; slot ^= row&7
__device__ __forceinline__ int swz64(int row, int col) {
  return row*64 + ((((col >> 3) ^ (row & 7)) << 3) | (col & 7));
}

__device__ __forceinline__ unsigned pkbf(float a, float b) {
  __hip_bfloat162 h = __float22bfloat162_rn(make_float2(a, b)); // x=lo, y=hi
  return *reinterpret_cast<unsigned*>(&h);
}

// permlane swaps (VALU pipe). Verified row semantics (involutions):
// perm16(d,s): d'=[d0,s0,d2,s2], s'=[d1,s1,d3,s3]   (16-lane rows)
// perm32(d,s): d'=[d0,d1,s0,s1], s'=[d2,d3,s2,s3]
__device__ __forceinline__ void perm16p(unsigned &a, unsigned &b) {
  asm("v_permlane16_swap_b32 %0, %1" : "+v"(a), "+v"(b));
}
__device__ __forceinline__ void perm32p(unsigned &a, unsigned &b) {
  asm("v_permlane32_swap_b32 %0, %1" : "+v"(a), "+v"(b));
}

// inline-asm LDS reads (opaque to alias analysis: no compiler-inserted vmcnt drains)
__device__ __forceinline__ short8 ldsr_o0(unsigned a) {
  short8 r; asm volatile("ds_read_b128 %0, %1" : "=v"(r) : "v"(a)); return r;
}
__device__ __forceinline__ short8 ldsr_o1(unsigned a) {
  short8 r; asm volatile("ds_read_b128 %0, %1 offset:2048" : "=v"(r) : "v"(a)); return r;
}
__device__ __forceinline__ short8 ldsr_o2(unsigned a) {
  short8 r; asm volatile("ds_read_b128 %0, %1 offset:4096" : "=v"(r) : "v"(a)); return r;
}
__device__ __forceinline__ short8 ldsr_o3(unsigned a) {
  short8 r; asm volatile("ds_read_b128 %0, %1 offset:6144" : "=v"(r) : "v"(a)); return r;
}
__device__ __forceinline__ short8 ldsr_o4(unsigned a) {
  short8 r; asm volatile("ds_read_b128 %0, %1 offset:8192" : "=v"(r) : "v"(a)); return r;
}
__device__ __forceinline__ short8 ldsr_o5(unsigned a) {
  short8 r; asm volatile("ds_read_b128 %0, %1 offset:10240" : "=v"(r) : "v"(a)); return r;
}

#define LGKM0  do { asm volatile("s_waitcnt lgkmcnt(0)"); __builtin_amdgcn_sched_barrier(0); } while(0)
#define VMCNT6 do { __builtin_amdgcn_sched_barrier(0); asm volatile("s_waitcnt vmcnt(6)"); __builtin_amdgcn_sched_barrier(0); } while(0)
#define VMCNT0 do { __builtin_amdgcn_sched_barrier(0); asm volatile("s_waitcnt vmcnt(0)"); __builtin_amdgcn_sched_barrier(0); } while(0)
#define BARRIER do { __builtin_amdgcn_s_barrier(); __builtin_amdgcn_sched_barrier(0); } while(0)

// ---------------- fp32 -> bf16 copy convert ----------------
__global__ __launch_bounds__(256) void k_cvt(const float* __restrict__ in,
                                             __hip_bfloat16* __restrict__ out, int n8) {
  int i = blockIdx.x * 256 + threadIdx.x;
  if (i >= n8) return;
  const float* p = in + (size_t)i * 8;
  short8 o;
#pragma unroll
  for (int j = 0; j < 8; ++j) {
    __hip_bfloat16 h = __float2bfloat16(p[j]);
    o[j] = *reinterpret_cast<short*>(&h);
  }
  *reinterpret_cast<short8*>(out + (size_t)i * 8) = o;
}

// ---------------- W [K][N] fp32 -> Wt [N][K] bf16 (tiled transpose) ----------------
__global__ __launch_bounds__(256) void k_transpose_cvt(const float* __restrict__ W,
                                                       __hip_bfloat16* __restrict__ Wt,
                                                       int K, int N) {
  __shared__ float tbuf[32][33];
  const int n0 = blockIdx.x * 32, k0 = blockIdx.y * 32;
  const int tx = threadIdx.x & 31, ty = threadIdx.x >> 5;
#pragma unroll
  for (int i = 0; i < 4; ++i)
    tbuf[ty + i*8][tx] = W[(size_t)(k0 + ty + i*8) * N + n0 + tx];
  __syncthreads();
#pragma unroll
  for (int i = 0; i < 4; ++i)
    Wt[(size_t)(n0 + ty + i*8) * K + k0 + tx] = __float2bfloat16(tbuf[tx][ty + i*8]);
}

// ---------------- 256x192 double-buffered deep-pipeline QKV GEMM ----------------
// 512 threads / 8 waves (4m x 2n), per-wave 64x96 output. BK=64, 16 K-tiles.
// Stage tile t+1 while computing tile t; per-tile vmcnt(0)+barrier (loads waited
// were issued a full tile (~4000 cyc) earlier). Inline-asm ds_read_b128.
// Epilogue: per-16-col-group LDS bounce (wave cols straddle head/QKV boundaries).
__global__ __launch_bounds__(512, 2) void k_gemm3(const __hip_bfloat16* __restrict__ A,
                                                  const __hip_bfloat16* __restrict__ Bt,
                                                  const float* __restrict__ bias,
                                                  __hip_bfloat16* __restrict__ Qb,
                                                  __hip_bfloat16* __restrict__ Kb,
                                                  __hip_bfloat16* __restrict__ Vtb) {
  __shared__ __hip_bfloat16 As[2][256 * 64];
  __shared__ __hip_bfloat16 Bs[2][192 * 64];
  const int tid = threadIdx.x;
  const int l = tid & 63, w = tid >> 6;
  const int lr = l & 15, lg = l >> 4;
  const int wm = w >> 1, wn = w & 1;
  const int m0 = blockIdx.x * 256, n0 = blockIdx.y * 192;

  const int srow = tid >> 3;
  const int scol = (((tid & 7) ^ (srow & 7)) << 3);
  const size_t aoffs = (size_t)(m0 + srow) * 1024 + scol;
  const size_t boffs = (size_t)(n0 + srow) * 1024 + scol;
  const int ldst = tid * 8;

  auto stage = [&](int t, int s) {
    const int k0 = t * 64;
#pragma unroll
    for (int rd = 0; rd < 4; ++rd)
      gl_lds16(A + aoffs + (size_t)rd * 65536 + k0, &As[s][rd * 4096 + ldst]);
#pragma unroll
    for (int rd = 0; rd < 3; ++rd)
      gl_lds16(Bt + boffs + (size_t)rd * 65536 + k0, &Bs[s][rd * 4096 + ldst]);
  };

  const unsigned asLds = (unsigned)(uintptr_t)&As[0][0];
  const unsigned bsLds = (unsigned)(uintptr_t)&Bs[0][0];
  const unsigned aBase0 = asLds + 2u * ((wm*64 + lr) * 64 + ((lg ^ (lr & 7)) << 3));
  const unsigned bBase0 = bsLds + 2u * ((wn*96 + lr) * 64 + ((lg ^ (lr & 7)) << 3));

  stage(0, 0);
  VMCNT0;
  BARRIER;

  f32x4 acc[4][6] = {};
  short8 a_[4][2], b_[3][2];

#pragma unroll
  for (int t = 0; t < 16; ++t) {
    const int s = t & 1;
    const unsigned aB0 = aBase0 + (unsigned)s * 32768u;
    const unsigned aB1 = aB0 ^ 64u;
    const unsigned bB0 = bBase0 + (unsigned)s * 24576u;
    const unsigned bB1 = bB0 ^ 64u;
    if (t < 15) stage(t + 1, s ^ 1);
    // phase A: A frags + B n0..2, MFMA n=0..2
    a_[0][0] = ldsr_o0(aB0); a_[1][0] = ldsr_o1(aB0); a_[2][0] = ldsr_o2(aB0); a_[3][0] = ldsr_o3(aB0);
    a_[0][1] = ldsr_o0(aB1); a_[1][1] = ldsr_o1(aB1); a_[2][1] = ldsr_o2(aB1); a_[3][1] = ldsr_o3(aB1);
    b_[0][0] = ldsr_o0(bB0); b_[1][0] = ldsr_o1(bB0); b_[2][0] = ldsr_o2(bB0);
    b_[0][1] = ldsr_o0(bB1); b_[1][1] = ldsr_o1(bB1); b_[2][1] = ldsr_o2(bB1);
    LGKM0;
    __builtin_amdgcn_s_setprio(1);
#pragma unroll
    for (int m = 0; m < 4; ++m)
#pragma unroll
      for (int n = 0; n < 3; ++n)
#pragma unroll
        for (int ks = 0; ks < 2; ++ks)
          acc[m][n] = mfma16(a_[m][ks], b_[n][ks], acc[m][n]);
    __builtin_amdgcn_s_setprio(0);
    // phase B: B n3..5, MFMA n=3..5
    b_[0][0] = ldsr_o3(bB0); b_[1][0] = ldsr_o4(bB0); b_[2][0] = ldsr_o5(bB0);
    b_[0][1] = ldsr_o3(bB1); b_[1][1] = ldsr_o4(bB1); b_[2][1] = ldsr_o5(bB1);
    LGKM0;
    __builtin_amdgcn_s_setprio(1);
#pragma unroll
    for (int m = 0; m < 4; ++m)
#pragma unroll
      for (int n = 0; n < 3; ++n)
#pragma unroll
        for (int ks = 0; ks < 2; ++ks)
          acc[m][n + 3] = mfma16(a_[m][ks], b_[n][ks], acc[m][n + 3]);
    __builtin_amdgcn_s_setprio(0);
    if (t < 15) { VMCNT0; }
    BARRIER;
  }

  __syncthreads();
  // ---- per-16-col-group LDS-bounce epilogue ----
  // wave-private region: 6 groups x 1024 elems (final tile used slot 1; regions in slot 0)
  __hip_bfloat16* reg = (w < 4) ? (&As[0][0] + w * 6144)
                                : (&Bs[0][0] + (w - 4) * 6144);
  const int colbase = n0 + wn * 96;
  const int rowbase = m0 + wm * 64;
  const int bidx = rowbase >> 11;
  const int tbase = rowbase & 2047;
  const float qs = 0.18033688011112042f;   // 0.125 * log2(e) folded into Q
  float bv[6];
#pragma unroll
  for (int g = 0; g < 6; ++g) bv[g] = bias[colbase + g * 16 + lr];
#pragma unroll
  for (int g = 0; g < 6; ++g) {
    const int cg0 = colbase + g * 16;
    const int which = cg0 >> 10;
    __hip_bfloat16* rg = reg + g * 1024;
    if (which == 2) {
      // V group: region [d=lr][t], t XOR-swizzled by (lr&7)<<3
#pragma unroll
      for (int m = 0; m < 4; ++m)
#pragma unroll
        for (int r = 0; r < 4; ++r) {
          const int t = m * 16 + lg * 4 + r;
          rg[lr * 64 + (t ^ ((lr & 7) << 3))] = __float2bfloat16(acc[m][g][r] + bv[g]);
        }
    } else {
      const float sc = (which == 0) ? qs : 1.f;
#pragma unroll
      for (int m = 0; m < 4; ++m)
#pragma unroll
        for (int r = 0; r < 4; ++r) {
          const int t = m * 16 + lg * 4 + r;
          rg[t * 16 + (lr ^ (((t >> 2) & 1) << 3))] =
              __float2bfloat16((acc[m][g][r] + bv[g]) * sc);
        }
    }
  }
#pragma unroll
  for (int g = 0; g < 6; ++g) {
    const int cg0 = colbase + g * 16;
    const int which = cg0 >> 10;
    const int hh = (cg0 >> 6) & 15;
    const int dd0 = cg0 & 48;
    const size_t bh = (size_t)bidx * 16 + hh;
    const __hip_bfloat16* rg = reg + g * 1024;
    if (which < 2) {
      __hip_bfloat16* basep = (which == 0) ? Qb : Kb;
      const int t = l;
      const int Xc = ((t >> 2) & 1) << 3;
      short8 y0 = *reinterpret_cast<const short8*>(&rg[t * 16 + Xc]);        // c 0..7
      short8 y1 = *reinterpret_cast<const short8*>(&rg[t * 16 + (Xc ^ 8)]);  // c 8..15
      __hip_bfloat16* dst = basep + (bh * TT + tbase + t) * 64 + dd0;
      *reinterpret_cast<short8*>(dst) = y0;
      *reinterpret_cast<short8*>(dst + 8) = y1;
    } else {
      const int dd = l >> 2, tseg = l & 3;
      const int X = (dd & 7) << 3;
      const int S0 = (((tseg ^ (X >> 4)) & 3) << 4) | (X & 8);
      short8 y0 = *reinterpret_cast<const short8*>(&rg[dd * 64 + S0]);        // t +0..7
      short8 y1 = *reinterpret_cast<const short8*>(&rg[dd * 64 + (S0 ^ 8)]);  // t +8..15
      __hip_bfloat16* dst = Vtb + (bh * 64 + dd0 + dd) * TT + tbase + tseg * 16;
      *reinterpret_cast<short8*>(dst) = y0;
      *reinterpret_cast<short8*>(dst + 8) = y1;
    }
  }
}

// ---------------- 256x128 triple-buffered deep-pipeline GEMM (proj) ----------------
__global__ __launch_bounds__(512, 2) void k_gemm2(const __hip_bfloat16* __restrict__ A,
                                                  const __hip_bfloat16* __restrict__ Bt,
                                                  const float* __restrict__ bias,
                                                  float* __restrict__ outF) {
  __shared__ __hip_bfloat16 As[3][256 * 64];
  __shared__ __hip_bfloat16 Bs[3][128 * 64];
  const int tid = threadIdx.x;
  const int l = tid & 63, w = tid >> 6;
  const int lr = l & 15, lg = l >> 4;
  const int wm = w >> 1, wn = w & 1;
  const int m0 = blockIdx.x * 256, n0 = blockIdx.y * 128;

  const int srow = tid >> 3;
  const int scol = (((tid & 7) ^ (srow & 7)) << 3);
  const size_t aoffs = (size_t)(m0 + srow) * 1024 + scol;
  const size_t boffs = (size_t)(n0 + srow) * 1024 + scol;
  const int ldst = tid * 8;

  auto stage = [&](int t, int s) {
    const int k0 = t * 64;
    __hip_bfloat16* as_ = &As[s][0];
    __hip_bfloat16* bs_ = &Bs[s][0];
#pragma unroll
    for (int rd = 0; rd < 4; ++rd)
      gl_lds16(A + aoffs + (size_t)rd * 65536 + k0, as_ + rd * 4096 + ldst);
#pragma unroll
    for (int rd = 0; rd < 2; ++rd)
      gl_lds16(Bt + boffs + (size_t)rd * 65536 + k0, bs_ + rd * 4096 + ldst);
  };

  const unsigned asLds = (unsigned)(uintptr_t)&As[0][0];
  const unsigned bsLds = (unsigned)(uintptr_t)&Bs[0][0];
  const unsigned aBase = asLds + 2u * ((wm*64 + lr) * 64 + ((lg ^ (lr & 7)) << 3));
  const unsigned bBase = bsLds + 2u * ((wn*64 + lr) * 64 + ((lg ^ (lr & 7)) << 3));

  stage(0, 0);
  stage(1, 1);
  VMCNT6;
  BARRIER;

  f32x4 acc[4][4] = {};
  short8 a_[4][2], b_[2][2];

#pragma unroll
  for (int t = 0; t < 16; ++t) {
    const int s = t % 3;
    const unsigned aB0 = aBase + (unsigned)s * 32768u;
    const unsigned aB1 = aB0 ^ 64u;
    const unsigned bB0 = bBase + (unsigned)s * 16384u;
    const unsigned bB1 = bB0 ^ 64u;
    if (t + 2 < 16) stage(t + 2, (t + 2) % 3);
    a_[0][0] = ldsr_o0(aB0); a_[1][0] = ldsr_o1(aB0); a_[2][0] = ldsr_o2(aB0); a_[3][0] = ldsr_o3(aB0);
    a_[0][1] = ldsr_o0(aB1); a_[1][1] = ldsr_o1(aB1); a_[2][1] = ldsr_o2(aB1); a_[3][1] = ldsr_o3(aB1);
    b_[0][0] = ldsr_o0(bB0); b_[1][0] = ldsr_o1(bB0);
    b_[0][1] = ldsr_o0(bB1); b_[1][1] = ldsr_o1(bB1);
    LGKM0;
    __builtin_amdgcn_s_setprio(1);
#pragma unroll
    for (int m = 0; m < 4; ++m)
#pragma unroll
      for (int n = 0; n < 2; ++n)
#pragma unroll
        for (int ks = 0; ks < 2; ++ks)
          acc[m][n] = mfma16(a_[m][ks], b_[n][ks], acc[m][n]);
    __builtin_amdgcn_s_setprio(0);
    b_[0][0] = ldsr_o2(bB0); b_[1][0] = ldsr_o3(bB0);
    b_[0][1] = ldsr_o2(bB1); b_[1][1] = ldsr_o3(bB1);
    LGKM0;
    __builtin_amdgcn_s_setprio(1);
#pragma unroll
    for (int m = 0; m < 4; ++m)
#pragma unroll
      for (int n = 0; n < 2; ++n)
#pragma unroll
        for (int ks = 0; ks < 2; ++ks)
          acc[m][n + 2] = mfma16(a_[m][ks], b_[n][ks], acc[m][n + 2]);
    __builtin_amdgcn_s_setprio(0);
    if (t <= 13) { VMCNT6; }
    else if (t == 14) { VMCNT0; }
    BARRIER;
  }

  __syncthreads();
#pragma unroll
  for (int n = 0; n < 4; ++n) {
    const int col = n0 + wn * 64 + n * 16 + lr;
    const float bvv = bias[col];
#pragma unroll
    for (int m = 0; m < 4; ++m)
#pragma unroll
      for (int r = 0; r < 4; ++r) {
        const int row = m0 + wm * 64 + m * 16 + lg * 4 + r;
        outF[(size_t)row * 1024 + col] = acc[m][n][r] + bvv;
      }
  }
}

// ---------------- causal flash attention ----------------
// Merged paired q-tiles, fixed-max softmax, sigma-permuted K rows so the P->PV
// redistribution is exactly 2x permlane16_swap + 2x permlane32_swap (no cndmask).
__device__ __forceinline__ void tile_step(f32x4 s0, f32x4 s1, int kbase, int kmaxw, int qmb,
                                          short8 v0, short8 v1, short8 v2, short8 v3,
                                          f32x4 (&acc)[4], float& lrun) {
  if (kbase + 31 > kmaxw - 15) {       // diagonal chunk: per-element causal mask
#pragma unroll
    for (int r = 0; r < 4; ++r) {
      const int off = (r & 1) + ((r & 2) << 2);   // 0,1,8,9
      if (kbase + off > qmb)      s0[r] = -INFINITY;
      if (kbase + 16 + off > qmb) s1[r] = -INFINITY;
    }
  }
  float p0 = __builtin_amdgcn_exp2f(s0[0]), p1 = __builtin_amdgcn_exp2f(s0[1]);
  float p2 = __builtin_amdgcn_exp2f(s0[2]), p3 = __builtin_amdgcn_exp2f(s0[3]);
  float p4 = __builtin_amdgcn_exp2f(s1[0]), p5 = __builtin_amdgcn_exp2f(s1[1]);
  float p6 = __builtin_amdgcn_exp2f(s1[2]), p7 = __builtin_amdgcn_exp2f(s1[3]);
  lrun += ((p0 + p1) + (p2 + p3)) + ((p4 + p5) + (p6 + p7));
  unsigned u0 = pkbf(p0, p1);
  unsigned u1 = pkbf(p2, p3);
  unsigned u2 = pkbf(p4, p5);
  unsigned u3 = pkbf(p6, p7);
  perm16p(u0, u1);
  perm16p(u2, u3);
  perm32p(u0, u2);
  perm32p(u1, u3);
  union { unsigned u[4]; short8 s; } pw;
  pw.u[0] = u0; pw.u[1] = u2; pw.u[2] = u1; pw.u[3] = u3;
  const short8 pf = pw.s;
  acc[0] = mfma16(v0, pf, acc[0]);
  acc[1] = mfma16(v1, pf, acc[1]);
  acc[2] = mfma16(v2, pf, acc[2]);
  acc[3] = mfma16(v3, pf, acc[3]);
}

__device__ __forceinline__ void store_tile(__hip_bfloat16* Ylds, f32x4 (&acc)[4],
                                           float lrun, int q0, int w, int l,
                                           int lr, int lg, int bh,
                                           __hip_bfloat16* __restrict__ Y) {
  lrun += __shfl_xor(lrun, 16);
  lrun += __shfl_xor(lrun, 32);
  const float inv = 1.f / lrun;
#pragma unroll
  for (int nb = 0; nb < 4; ++nb) {
#pragma unroll
    for (int r = 0; r < 4; ++r) {
      const int d = nb * 16 + lg * 4 + r;
      Ylds[swz64(lr, d)] = __float2bfloat16(acc[nb][r] * inv);
    }
  }
  const int rr = l >> 2, part = l & 3;
  const int trow = q0 + w * 16 + rr;
  const int b = bh >> 4, h = bh & 15;
  short8 y0 = *reinterpret_cast<const short8*>(&Ylds[swz64(rr, part * 16)]);
  short8 y1 = *reinterpret_cast<const short8*>(&Ylds[swz64(rr, part * 16 + 8)]);
  __hip_bfloat16* dst = Y + ((size_t)b * TT + trow) * 1024 + h * 64 + part * 16;
  *reinterpret_cast<short8*>(dst) = y0;
  *reinterpret_cast<short8*>(dst + 8) = y1;
}

__global__ __launch_bounds__(256, 4) void k_flash(const __hip_bfloat16* __restrict__ Qb,
                                                  const __hip_bfloat16* __restrict__ Kb,
                                                  const __hip_bfloat16* __restrict__ Vtb,
                                                  __hip_bfloat16* __restrict__ Y) {
  __shared__ __hip_bfloat16 Klds[128 * 64];
  __shared__ __hip_bfloat16 Vtlds[64 * 128];
  const int tid = threadIdx.x;
  const int l = tid & 63, w = tid >> 6;
  const int lr = l & 15, lg = l >> 4;
  const int p  = blockIdx.x >> 6;       // pair index 0..15
  const int bh = blockIdx.x & 63;
  const int q0A = p * 64, q0B = (31 - p) * 64;
  const __hip_bfloat16* Qp = Qb + (size_t)bh * TT * 64;
  const __hip_bfloat16* Kp = Kb + (size_t)bh * TT * 64;
  const __hip_bfloat16* Vp = Vtb + (size_t)bh * 64 * TT;
  const int qrowA = q0A + w * 16 + lr;
  const int qrowB = q0B + w * 16 + lr;
  const short8 qfA0 = *reinterpret_cast<const short8*>(Qp + (size_t)qrowA * 64 + lg * 8);
  const short8 qfA1 = *reinterpret_cast<const short8*>(Qp + (size_t)qrowA * 64 + 32 + lg * 8);
  const short8 qfB0 = *reinterpret_cast<const short8*>(Qp + (size_t)qrowB * 64 + lg * 8);
  const short8 qfB1 = *reinterpret_cast<const short8*>(Qp + (size_t)qrowB * 64 + 32 + lg * 8);
  f32x4 accA[4] = {}, accB[4] = {};
  float lA = 0.f, lB = 0.f;

  const int ka  = lr * 64 + ((lg ^ (lr & 7)) << 3);
  const int va  = lr * 128 + ((lg ^ (lr & 15)) << 3);

  const __hip_bfloat16* gk[4];
  const __hip_bfloat16* gv[4];
  __hip_bfloat16* lk[4];
  __hip_bfloat16* lv[4];
#pragma unroll
  for (int it = 0; it < 4; ++it) {
    int e = it * 2048 + tid * 8;
    int rowk = e >> 6;
    int lcolk = ((((e >> 3) & 7) ^ (rowk & 7)) << 3);
    int rk = rowk & 15;
    int srk = (((rk >> 1) ^ (rk >> 3)) & 1) ? (rk ^ 10) : rk;
    int rowks = (rowk & ~15) | srk;
    gk[it] = Kp + (size_t)rowks * 64 + lcolk;
    lk[it] = &Klds[e];
    int rowv = e >> 7;
    int lcolv = ((((e >> 3) & 15) ^ (rowv & 15)) << 3);
    gv[it] = Vp + (size_t)rowv * TT + lcolv;
    lv[it] = &Vtlds[e];
  }

  const int kmaxwA = q0A + w * 16 + 15;
  const int kmaxwB = q0B + w * 16 + 15;
  const int base_lg = ((lg & 1) << 2) | (lg & 2);
  const int qmbA = qrowA - base_lg;
  const int qmbB = qrowB - base_lg;
  const int nblk = (q0B + 63) / 128 + 1;
  for (int blk = 0; blk < nblk; ++blk) {
    const int kv0 = blk * 128;
#pragma unroll
    for (int it = 0; it < 4; ++it) {
      gl_lds16(gk[it], lk[it]);
      gk[it] += 128 * 64;
    }
#pragma unroll
    for (int it = 0; it < 4; ++it) {
      gl_lds16(gv[it], lv[it]);
      gv[it] += 128;
    }
    __syncthreads();
#pragma unroll
    for (int kci = 0; kci < 4; ++kci) {
      const int kbase = kv0 + kci * 32;
      if (kbase > kmaxwB) break;
      const int kb = ka + kci * 2048;
      const short8 kf00 = *reinterpret_cast<const short8*>(&Klds[kb]);
      const short8 kf10 = *reinterpret_cast<const short8*>(&Klds[kb + 1024]);
      const short8 kf01 = *reinterpret_cast<const short8*>(&Klds[kb ^ 32]);
      const short8 kf11 = *reinterpret_cast<const short8*>(&Klds[(kb + 1024) ^ 32]);
      f32x4 sB0 = {}, sB1 = {};
      sB0 = mfma16(kf00, qfB0, sB0);
      sB1 = mfma16(kf10, qfB0, sB1);
      sB0 = mfma16(kf01, qfB1, sB0);
      sB1 = mfma16(kf11, qfB1, sB1);
      const bool aAct = (kbase <= kmaxwA);
      f32x4 sA0 = {}, sA1 = {};
      if (aAct) {
        sA0 = mfma16(kf00, qfA0, sA0);
        sA1 = mfma16(kf10, qfA0, sA1);
        sA0 = mfma16(kf01, qfA1, sA0);
        sA1 = mfma16(kf11, qfA1, sA1);
      }
      const int vb = va ^ (kci * 32);
      const short8 v0 = *reinterpret_cast<const short8*>(&Vtlds[vb]);
      const short8 v1 = *reinterpret_cast<const short8*>(&Vtlds[vb + 2048]);
      const short8 v2 = *reinterpret_cast<const short8*>(&Vtlds[vb + 4096]);
      const short8 v3 = *reinterpret_cast<const short8*>(&Vtlds[vb + 6144]);
      tile_step(sB0, sB1, kbase, kmaxwB, qmbB, v0, v1, v2, v3, accB, lB);
      if (aAct)
        tile_step(sA0, sA1, kbase, kmaxwA, qmbA, v0, v1, v2, v3, accA, lA);
    }
    __syncthreads();
  }
  __hip_bfloat16* Ylds = Klds + w * 1024;
  store_tile(Ylds, accA, lA, q0A, w, l, lr, lg, bh, Y);
  store_tile(Ylds, accB, lB, q0B, w, l, lr, lg, bh, Y);
}

// ---------------- launch ----------------
extern "C" void kernel_launch(void* const* d_in, const int* in_sizes, int n_in,
                              void* d_out, int out_size, void* d_ws, size_t ws_size,
                              hipStream_t stream) {
  const float* x     = (const float*)d_in[0];
  const float* Wqkv  = (const float*)d_in[1];
  const float* bqkv  = (const float*)d_in[2];
  const float* Wproj = (const float*)d_in[3];
  const float* bproj = (const float*)d_in[4];

  char* ws = (char*)d_ws;
  size_t off = 0;
  auto alloc = [&](size_t bytes) {
    char* p = ws + off;
    off += (bytes + 255) & ~(size_t)255;
    return p;
  };
  __hip_bfloat16* xb    = (__hip_bfloat16*)alloc((size_t)MTOT * 1024 * 2);
  __hip_bfloat16* wqkvT = (__hip_bfloat16*)alloc((size_t)3072 * 1024 * 2);
  __hip_bfloat16* wpT   = (__hip_bfloat16*)alloc((size_t)1024 * 1024 * 2);
  __hip_bfloat16* Qb    = (__hip_bfloat16*)alloc((size_t)64 * TT * 64 * 2);
  __hip_bfloat16* Kb    = (__hip_bfloat16*)alloc((size_t)64 * TT * 64 * 2);
  __hip_bfloat16* Vtb   = (__hip_bfloat16*)alloc((size_t)64 * TT * 64 * 2);
  __hip_bfloat16* Yb    = (__hip_bfloat16*)alloc((size_t)MTOT * 1024 * 2);

  k_cvt<<<(MTOT * 1024 / 8 + 255) / 256, 256, 0, stream>>>(x, xb, MTOT * 1024 / 8);
  k_transpose_cvt<<<dim3(3072 / 32, 1024 / 32), 256, 0, stream>>>(Wqkv, wqkvT, 1024, 3072);
  k_transpose_cvt<<<dim3(1024 / 32, 1024 / 32), 256, 0, stream>>>(Wproj, wpT, 1024, 1024);
  k_gemm3<<<dim3(32, 16), 512, 0, stream>>>(xb, wqkvT, bqkv, Qb, Kb, Vtb);
  k_flash<<<16 * 64, 256, 0, stream>>>(Qb, Kb, Vtb, Yb);
  k_gemm2<<<dim3(32, 8), 512, 0, stream>>>(Yb, wpT, bproj, (float*)d_out);
}